// Round 1
// baseline (1235.260 us; speedup 1.0000x reference)
//
#include <hip/hip_runtime.h>
#include <hip/hip_bf16.h>
#include <math.h>

// ---------------------------------------------------------------------------
// Seq_HyGAN: hypergraph attention network, f32 end-to-end.
//   feat_e = efeat@Wfl+bfl; k_e=feat_e@W5+b5; v_e=feat_e@W6+b6; q_e=feat_e@W1+b1
//   q_v = vfeat@W4+b4
//   attn1 = leaky(dot(k_e[he], q_v[nd]))*scale ; segment-softmax over nd
//   feat_v = segsum(a1 * v_e[he]) by nd
//   k_v=feat_v@W2+b2; v_v=feat_v@W3+b3
//   attn2 = leaky(dot(k_v[nd], q_e[he]))*scale ; segment-softmax over he
//   feat_e2 = segsum(a2 * v_v[nd]) by he
//   pred = feat_e2@Wc+bc
// ---------------------------------------------------------------------------

#define HY_M 10000
#define HY_N 100000
#define HY_E 640000

__device__ __forceinline__ void atomicMaxFloat(float* addr, float val) {
    // signed-int max for non-negative floats, unsigned-int min for negatives.
    if (val >= 0.f) atomicMax((int*)addr, __float_as_int(val));
    else            atomicMin((unsigned int*)addr, (unsigned int)__float_as_int(val));
}

__global__ void fillk(float* __restrict__ p, float v, int n) {
    int stride = gridDim.x * blockDim.x;
    for (int i = blockIdx.x * blockDim.x + threadIdx.x; i < n; i += stride) p[i] = v;
}

// C[r][j] = sum_k A[r][k] * W[k][j] + b[j]; K=N=128 fixed, 64-row tiles.
// 512 threads: cg = tid&31 -> cols 4*cg..+3 ; rs = tid>>5 -> rows 4*rs..+3
__launch_bounds__(512)
__global__ void gemm128(const float* __restrict__ A, const float* __restrict__ W,
                        const float* __restrict__ b, float* __restrict__ C, int nrows) {
    __shared__ __align__(16) float wlds[128 * 128];   // 64 KB
    __shared__ __align__(16) float at[128 * 68];      // transposed A tile, padded
    const int tid = threadIdx.x;
    {   // stage W (vectorized, coalesced)
        const float4* src = (const float4*)W;
        float4* dst = (float4*)wlds;
        for (int i = tid; i < 128 * 128 / 4; i += 512) dst[i] = src[i];
    }
    const int rowbase = blockIdx.x * 64;
    for (int i = tid; i < 64 * 128; i += 512) {       // stage A transposed
        int r = i >> 7, k = i & 127;
        int gr = rowbase + r;
        at[k * 68 + r] = (gr < nrows) ? A[(size_t)gr * 128 + k] : 0.f;
    }
    __syncthreads();
    const int cg = tid & 31;
    const int rs = tid >> 5;
    float acc[4][4] = {};
    #pragma unroll 4
    for (int k = 0; k < 128; ++k) {
        const float4 av = *(const float4*)&at[k * 68 + rs * 4];
        const float4 wv = *(const float4*)&wlds[k * 128 + cg * 4];
        float a4[4] = {av.x, av.y, av.z, av.w};
        float w4[4] = {wv.x, wv.y, wv.z, wv.w};
        #pragma unroll
        for (int r = 0; r < 4; ++r)
            #pragma unroll
            for (int c = 0; c < 4; ++c)
                acc[r][c] = fmaf(a4[r], w4[c], acc[r][c]);
    }
    const float4 bv = *(const float4*)&b[cg * 4];
    #pragma unroll
    for (int r = 0; r < 4; ++r) {
        int gr = rowbase + rs * 4 + r;
        if (gr < nrows) {
            float4 o = {acc[r][0] + bv.x, acc[r][1] + bv.y,
                        acc[r][2] + bv.z, acc[r][3] + bv.w};
            *(float4*)&C[(size_t)gr * 128 + cg * 4] = o;
        }
    }
}

// per-edge: logit = leaky_relu(dot(X[xi[e]], Y[yi[e]])) * scale ; segmax[yi[e]] max=
// one 64-lane wave per edge, shuffle reduction
__launch_bounds__(256)
__global__ void edge_attn(const float* __restrict__ X, const float* __restrict__ Y,
                          const int* __restrict__ xi, const int* __restrict__ yi,
                          float* __restrict__ logits, float* __restrict__ segmax,
                          int E, float scale) {
    int wid = (blockIdx.x * blockDim.x + threadIdx.x) >> 6;
    int lane = threadIdx.x & 63;
    if (wid >= E) return;
    int a = xi[wid], bseg = yi[wid];
    const float* xr = X + (size_t)a * 128;
    const float* yr = Y + (size_t)bseg * 128;
    float s = xr[lane] * yr[lane] + xr[lane + 64] * yr[lane + 64];
    #pragma unroll
    for (int off = 32; off; off >>= 1) s += __shfl_xor(s, off, 64);
    if (lane == 0) {
        float l = (s >= 0.f ? s : 0.01f * s) * scale;
        logits[wid] = l;
        atomicMaxFloat(&segmax[bseg], l);
    }
}

// e[e] = exp(logit - segmax[dst]); segsum[dst] += e
__global__ void edge_exp(const float* __restrict__ logits, const float* __restrict__ segmax,
                         const int* __restrict__ dst, float* __restrict__ ev,
                         float* __restrict__ segsum, int E) {
    int e = blockIdx.x * blockDim.x + threadIdx.x;
    if (e >= E) return;
    int d = dst[e];
    float v = expf(logits[e] - segmax[d]);
    ev[e] = v;
    atomicAdd(&segsum[d], v);
}

// out[dst[e]][:] += (ev[e]/segsum[dst[e]]) * V[vidx[e]][:]   (thread = (edge,dim))
__launch_bounds__(256)
__global__ void edge_scatter(const float* __restrict__ ev, const float* __restrict__ segsum,
                             const int* __restrict__ dst, const int* __restrict__ vidx,
                             const float* __restrict__ V, float* __restrict__ out, int E) {
    int t = blockIdx.x * blockDim.x + threadIdx.x;
    int e = t >> 7, d = t & 127;
    if (e >= E) return;
    int dr = dst[e];
    float s = segsum[dr];
    float w = ev[e] / (s > 0.f ? s : 1.f);
    atomicAdd(&out[(size_t)dr * 128 + d], w * V[(size_t)vidx[e] * 128 + d]);
}

// pred[m][c] = sum_k feat_e2[m][k]*Wc[k][c] + bc[c]
__global__ void head10(const float* __restrict__ X, const float* __restrict__ Wc,
                       const float* __restrict__ bc, float* __restrict__ out, int M) {
    int t = blockIdx.x * blockDim.x + threadIdx.x;
    if (t >= M * 10) return;
    int row = t / 10, c = t % 10;
    float acc = bc[c];
    #pragma unroll 8
    for (int k = 0; k < 128; ++k)
        acc = fmaf(X[(size_t)row * 128 + k], Wc[k * 10 + c], acc);
    out[t] = acc;
}

extern "C" void kernel_launch(void* const* d_in, const int* in_sizes, int n_in,
                              void* d_out, int out_size, void* d_ws, size_t ws_size,
                              hipStream_t stream) {
    const float* vfeat = (const float*)d_in[0];
    const float* efeat = (const float*)d_in[1];
    const int*   he    = (const int*)d_in[2];
    const int*   nd    = (const int*)d_in[3];
    // d_in[4]=first_layer, d_in[5]=last_layer (always 1)
    const float* Wfl = (const float*)d_in[6],  *bfl = (const float*)d_in[7];
    const float* W1  = (const float*)d_in[8],  *b1  = (const float*)d_in[9];
    const float* W2  = (const float*)d_in[10], *b2  = (const float*)d_in[11];
    const float* W3  = (const float*)d_in[12], *b3  = (const float*)d_in[13];
    const float* W4  = (const float*)d_in[14], *b4  = (const float*)d_in[15];
    const float* W5  = (const float*)d_in[16], *b5  = (const float*)d_in[17];
    const float* W6  = (const float*)d_in[18], *b6  = (const float*)d_in[19];
    const float* Wc  = (const float*)d_in[20], *bc  = (const float*)d_in[21];
    float* out = (float*)d_out;
    float* ws  = (float*)d_ws;

    const int M = HY_M, N = HY_N, E = HY_E;

    // workspace layout (floats). zero-region [feat_v .. hsum] is contiguous.
    float* q_v     = ws + 0;          // 12.8M ; reused as k_v after attn1
    float* k_v     = q_v;
    float* v_v     = ws + 12800000;   // 12.8M
    float* feat_v  = ws + 25600000;   // 12.8M  (zero)
    float* feat_e2 = ws + 38400000;   // 1.28M  (zero)
    float* nsum    = ws + 39680000;   // 100K   (zero)
    float* hsum    = ws + 39780000;   // 10K    (zero)
    float* nmax    = ws + 39790000;   // 100K   (-inf)
    float* hmax    = ws + 39890000;   // 10K    (-inf)
    float* logits  = ws + 39900000;   // 640K
    float* ev      = ws + 40540000;   // 640K
    float* feat_e  = ws + 41180000;   // 1.28M
    float* k_e     = ws + 42460000;   // 1.28M
    float* v_e     = ws + 43740000;   // 1.28M
    float* q_e     = ws + 45020000;   // 1.28M
    // total 46.3M floats = 185.2 MB

    const float scale = 0.08838834764831843f;  // 1/sqrt(128)

    fillk<<<2048, 256, 0, stream>>>(feat_v, 0.f, 14190000);
    fillk<<<128, 256, 0, stream>>>(nmax, -INFINITY, 110000);

    // efeat-path GEMMs (M rows)
    gemm128<<<(M + 63) / 64, 512, 0, stream>>>(efeat, Wfl, bfl, feat_e, M);
    gemm128<<<(M + 63) / 64, 512, 0, stream>>>(feat_e, W5, b5, k_e, M);
    gemm128<<<(M + 63) / 64, 512, 0, stream>>>(feat_e, W6, b6, v_e, M);
    gemm128<<<(M + 63) / 64, 512, 0, stream>>>(feat_e, W1, b1, q_e, M);
    // node-path GEMM (N rows)
    gemm128<<<(N + 63) / 64, 512, 0, stream>>>(vfeat, W4, b4, q_v, N);

    // stage 1: hyperedge -> node
    edge_attn<<<(E + 3) / 4, 256, 0, stream>>>(k_e, q_v, he, nd, logits, nmax, E, scale);
    edge_exp<<<(E + 255) / 256, 256, 0, stream>>>(logits, nmax, nd, ev, nsum, E);
    edge_scatter<<<E / 2, 256, 0, stream>>>(ev, nsum, nd, he, v_e, feat_v, E);

    gemm128<<<(N + 63) / 64, 512, 0, stream>>>(feat_v, W2, b2, k_v, N);
    gemm128<<<(N + 63) / 64, 512, 0, stream>>>(feat_v, W3, b3, v_v, N);

    // stage 2: node -> hyperedge
    edge_attn<<<(E + 3) / 4, 256, 0, stream>>>(k_v, q_e, nd, he, logits, hmax, E, scale);
    edge_exp<<<(E + 255) / 256, 256, 0, stream>>>(logits, hmax, he, ev, hsum, E);
    edge_scatter<<<E / 2, 256, 0, stream>>>(ev, hsum, he, nd, v_v, feat_e2, E);

    head10<<<(M * 10 + 255) / 256, 256, 0, stream>>>(feat_e2, Wc, bc, out, M);
}

// Round 2
// 808.204 us; speedup vs baseline: 1.5284x; 1.5284x over previous
//
#include <hip/hip_runtime.h>
#include <hip/hip_bf16.h>
#include <math.h>

// ---------------------------------------------------------------------------
// Seq_HyGAN: hypergraph attention, f32. Round 2: CSR-gather formulation.
//   Scatter-atomics (552us, 2x327MB HBM write-through) replaced by on-device
//   CSR build + one fused per-destination attention kernel per stage
//   (dot -> leaky -> online softmax -> weighted accumulate, registers only).
// ---------------------------------------------------------------------------

#define HY_M 10000
#define HY_N 100000
#define HY_E 640000

// ---------------- small utility kernels ----------------
__global__ void zero_ints(int* __restrict__ p, int n) {
    int i = blockIdx.x * blockDim.x + threadIdx.x;
    if (i < n) p[i] = 0;
}

__global__ void hist_kernel(const int* __restrict__ dst, int* __restrict__ cnt, int E) {
    int e = blockIdx.x * blockDim.x + threadIdx.x;
    if (e < E) atomicAdd(&cnt[dst[e]], 1);
}

// ---- 3-phase exclusive scan over n ints (chunk = 1024 per block) ----
__global__ void scanA(const int* __restrict__ cnt, int* __restrict__ bsum, int n) {
    __shared__ int s[256];
    int t = threadIdx.x, base = blockIdx.x * 1024;
    int v = 0;
    for (int i = t; i < 1024; i += 256) { int g = base + i; if (g < n) v += cnt[g]; }
    s[t] = v; __syncthreads();
    for (int off = 128; off; off >>= 1) { if (t < off) s[t] += s[t + off]; __syncthreads(); }
    if (t == 0) bsum[blockIdx.x] = s[0];
}

__global__ void scanB(int* __restrict__ bsum, int nb) {   // single block, nb<=256
    __shared__ int s[256];
    int t = threadIdx.x;
    int orig = (t < nb) ? bsum[t] : 0;
    s[t] = orig; __syncthreads();
    for (int off = 1; off < 256; off <<= 1) {
        int v = (t >= off) ? s[t - off] : 0;
        __syncthreads(); s[t] += v; __syncthreads();
    }
    if (t < nb) bsum[t] = s[t] - orig;  // exclusive
}

__global__ void scanC(const int* __restrict__ cnt, const int* __restrict__ bsum,
                      int* __restrict__ off, int n, int total) {
    __shared__ int s[256];
    int t = threadIdx.x, base = blockIdx.x * 1024;
    int idx = base + t * 4;
    int v[4], sum = 0;
    #pragma unroll
    for (int j = 0; j < 4; ++j) { v[j] = (idx + j < n) ? cnt[idx + j] : 0; sum += v[j]; }
    int orig = sum;
    s[t] = sum; __syncthreads();
    for (int o = 1; o < 256; o <<= 1) {
        int x = (t >= o) ? s[t - o] : 0;
        __syncthreads(); s[t] += x; __syncthreads();
    }
    int excl = s[t] - orig + bsum[blockIdx.x];
    #pragma unroll
    for (int j = 0; j < 4; ++j) { if (idx + j < n) off[idx + j] = excl; excl += v[j]; }
    if (blockIdx.x == 0 && t == 0) off[n] = total;
}

__global__ void fill_csr(const int* __restrict__ dst, const int* __restrict__ off,
                         int* __restrict__ cursor, int* __restrict__ eid, int E) {
    int e = blockIdx.x * blockDim.x + threadIdx.x;
    if (e >= E) return;
    int d = dst[e];
    int p = atomicAdd(&cursor[d], 1);
    eid[off[d] + p] = e;
}

// ---------------- dense f32 GEMM 128x128 weights, 64-row tiles ----------------
__launch_bounds__(512)
__global__ void gemm128(const float* __restrict__ A, const float* __restrict__ W,
                        const float* __restrict__ b, float* __restrict__ C, int nrows) {
    __shared__ __align__(16) float wlds[128 * 128];   // 64 KB
    __shared__ __align__(16) float at[128 * 68];      // transposed A tile, padded
    const int tid = threadIdx.x;
    {
        const float4* src = (const float4*)W;
        float4* dst = (float4*)wlds;
        for (int i = tid; i < 128 * 128 / 4; i += 512) dst[i] = src[i];
    }
    const int rowbase = blockIdx.x * 64;
    for (int i = tid; i < 64 * 128; i += 512) {
        int r = i >> 7, k = i & 127;
        int gr = rowbase + r;
        at[k * 68 + r] = (gr < nrows) ? A[(size_t)gr * 128 + k] : 0.f;
    }
    __syncthreads();
    const int cg = tid & 31;
    const int rs = tid >> 5;
    float acc[4][4] = {};
    #pragma unroll 4
    for (int k = 0; k < 128; ++k) {
        const float4 av = *(const float4*)&at[k * 68 + rs * 4];
        const float4 wv = *(const float4*)&wlds[k * 128 + cg * 4];
        float a4[4] = {av.x, av.y, av.z, av.w};
        float w4[4] = {wv.x, wv.y, wv.z, wv.w};
        #pragma unroll
        for (int r = 0; r < 4; ++r)
            #pragma unroll
            for (int c = 0; c < 4; ++c)
                acc[r][c] = fmaf(a4[r], w4[c], acc[r][c]);
    }
    const float4 bv = *(const float4*)&b[cg * 4];
    #pragma unroll
    for (int r = 0; r < 4; ++r) {
        int gr = rowbase + rs * 4 + r;
        if (gr < nrows) {
            float4 o = {acc[r][0] + bv.x, acc[r][1] + bv.y,
                        acc[r][2] + bv.z, acc[r][3] + bv.w};
            *(float4*)&C[(size_t)gr * 128 + cg * 4] = o;
        }
    }
}

// ---------------- fused per-destination attention stage ----------------
// one 64-lane wave per destination segment; online softmax in registers.
// out[seg] = sum_e softmax_e(leaky(dot(K[src[e]],Q[seg]))*scale) * V[src[e]]
__launch_bounds__(256)
__global__ void fused_attn(const float* __restrict__ Q, const float* __restrict__ K,
                           const float* __restrict__ V,
                           const int* __restrict__ off, const int* __restrict__ eid,
                           const int* __restrict__ src, float* __restrict__ out,
                           int nseg, float scale) {
    int seg = (blockIdx.x * blockDim.x + threadIdx.x) >> 6;
    int lane = threadIdx.x & 63;
    if (seg >= nseg) return;
    int beg = off[seg], end = off[seg + 1];
    float q0 = Q[(size_t)seg * 128 + lane];
    float q1 = Q[(size_t)seg * 128 + 64 + lane];
    float m = -INFINITY, l = 0.f, a0 = 0.f, a1 = 0.f;
    for (int i = beg; i < end; ++i) {
        int s = src[eid[i]];
        const float* kr = K + (size_t)s * 128;
        const float* vr = V + (size_t)s * 128;
        float d = kr[lane] * q0 + kr[lane + 64] * q1;
        #pragma unroll
        for (int o = 32; o; o >>= 1) d += __shfl_xor(d, o, 64);
        float logit = (d >= 0.f ? d : 0.01f * d) * scale;
        float mn = fmaxf(m, logit);
        float r = __expf(m - mn);          // first iter: exp(-inf) = 0
        float p = __expf(logit - mn);
        l  = l  * r + p;
        a0 = a0 * r + p * vr[lane];
        a1 = a1 * r + p * vr[lane + 64];
        m = mn;
    }
    float inv = (l > 0.f) ? 1.f / l : 0.f;  // empty segment -> zeros (matches ref)
    out[(size_t)seg * 128 + lane]      = a0 * inv;
    out[(size_t)seg * 128 + 64 + lane] = a1 * inv;
}

// ---------------- classification head ----------------
__global__ void head10(const float* __restrict__ X, const float* __restrict__ Wc,
                       const float* __restrict__ bc, float* __restrict__ out, int M) {
    int t = blockIdx.x * blockDim.x + threadIdx.x;
    if (t >= M * 10) return;
    int row = t / 10, c = t % 10;
    float acc = bc[c];
    #pragma unroll 8
    for (int k = 0; k < 128; ++k)
        acc = fmaf(X[(size_t)row * 128 + k], Wc[k * 10 + c], acc);
    out[t] = acc;
}

extern "C" void kernel_launch(void* const* d_in, const int* in_sizes, int n_in,
                              void* d_out, int out_size, void* d_ws, size_t ws_size,
                              hipStream_t stream) {
    const float* vfeat = (const float*)d_in[0];
    const float* efeat = (const float*)d_in[1];
    const int*   he    = (const int*)d_in[2];
    const int*   nd    = (const int*)d_in[3];
    const float* Wfl = (const float*)d_in[6],  *bfl = (const float*)d_in[7];
    const float* W1  = (const float*)d_in[8],  *b1  = (const float*)d_in[9];
    const float* W2  = (const float*)d_in[10], *b2  = (const float*)d_in[11];
    const float* W3  = (const float*)d_in[12], *b3  = (const float*)d_in[13];
    const float* W4  = (const float*)d_in[14], *b4  = (const float*)d_in[15];
    const float* W5  = (const float*)d_in[16], *b5  = (const float*)d_in[17];
    const float* W6  = (const float*)d_in[18], *b6  = (const float*)d_in[19];
    const float* Wc  = (const float*)d_in[20], *bc  = (const float*)d_in[21];
    float* out = (float*)d_out;
    float* ws  = (float*)d_ws;

    const int M = HY_M, N = HY_N, E = HY_E;

    // -------- workspace layout (4B elements), total 46.19M = 184.8 MB --------
    float* q_v     = ws + 0;           // 12.8M ; reused as k_v after stage 1
    float* k_v     = q_v;
    float* v_v     = ws + 12800000;    // 12.8M
    float* feat_v  = ws + 25600000;    // 12.8M (also CSR-build int scratch early)
    float* feat_e2 = ws + 38400000;    // 1.28M
    float* feat_e  = ws + 39680000;    // 1.28M
    float* k_e     = ws + 40960000;    // 1.28M
    float* v_e     = ws + 42240000;    // 1.28M
    float* q_e     = ws + 43520000;    // 1.28M
    int*   nd_off  = (int*)(ws + 44800000);   // 100001
    int*   he_off  = nd_off + 100001;         // 10001
    int*   nd_eid  = he_off + 10001;          // 640000
    int*   he_eid  = nd_eid + 640000;         // 640000
    // CSR-build scratch overlaps feat_v (dead until stage-1 attention writes it)
    int*   cnt     = (int*)feat_v;            // 100000
    int*   cursor  = cnt + 100000;            // 100000
    int*   bsum    = cursor + 100000;         // 128

    const float scale = 0.08838834764831843f;  // 1/sqrt(128)

    // -------- CSR build: edges grouped by nd (stage 1) and by he (stage 2) ----
    {   // by node
        int nb = (N + 1023) / 1024;  // 98
        zero_ints<<<(N + 255) / 256, 256, 0, stream>>>(cnt, N);
        hist_kernel<<<(E + 255) / 256, 256, 0, stream>>>(nd, cnt, E);
        scanA<<<nb, 256, 0, stream>>>(cnt, bsum, N);
        scanB<<<1, 256, 0, stream>>>(bsum, nb);
        scanC<<<nb, 256, 0, stream>>>(cnt, bsum, nd_off, N, E);
        zero_ints<<<(N + 255) / 256, 256, 0, stream>>>(cursor, N);
        fill_csr<<<(E + 255) / 256, 256, 0, stream>>>(nd, nd_off, cursor, nd_eid, E);
    }
    {   // by hyperedge
        int nb = (M + 1023) / 1024;  // 10
        zero_ints<<<(M + 255) / 256, 256, 0, stream>>>(cnt, M);
        hist_kernel<<<(E + 255) / 256, 256, 0, stream>>>(he, cnt, E);
        scanA<<<nb, 256, 0, stream>>>(cnt, bsum, M);
        scanB<<<1, 256, 0, stream>>>(bsum, nb);
        scanC<<<nb, 256, 0, stream>>>(cnt, bsum, he_off, M, E);
        zero_ints<<<(M + 255) / 256, 256, 0, stream>>>(cursor, M);
        fill_csr<<<(E + 255) / 256, 256, 0, stream>>>(he, he_off, cursor, he_eid, E);
    }

    // -------- dense layers (f32 VALU) --------
    gemm128<<<(M + 63) / 64, 512, 0, stream>>>(efeat, Wfl, bfl, feat_e, M);
    gemm128<<<(M + 63) / 64, 512, 0, stream>>>(feat_e, W5, b5, k_e, M);
    gemm128<<<(M + 63) / 64, 512, 0, stream>>>(feat_e, W6, b6, v_e, M);
    gemm128<<<(M + 63) / 64, 512, 0, stream>>>(feat_e, W1, b1, q_e, M);
    gemm128<<<(N + 63) / 64, 512, 0, stream>>>(vfeat, W4, b4, q_v, N);

    // -------- stage 1: hyperedge -> node (dest = node, one wave per node) ----
    fused_attn<<<(N * 64 + 255) / 256, 256, 0, stream>>>(
        q_v, k_e, v_e, nd_off, nd_eid, he, feat_v, N, scale);

    gemm128<<<(N + 63) / 64, 512, 0, stream>>>(feat_v, W2, b2, k_v, N);
    gemm128<<<(N + 63) / 64, 512, 0, stream>>>(feat_v, W3, b3, v_v, N);

    // -------- stage 2: node -> hyperedge (dest = hyperedge) ----
    fused_attn<<<(M * 64 + 255) / 256, 256, 0, stream>>>(
        q_e, k_v, v_v, he_off, he_eid, nd, feat_e2, M, scale);

    head10<<<(M * 10 + 255) / 256, 256, 0, stream>>>(feat_e2, Wc, bc, out, M);
}

// Round 3
// 586.517 us; speedup vs baseline: 2.1061x; 1.3780x over previous
//
#include <hip/hip_runtime.h>
#include <hip/hip_bf16.h>
#include <math.h>

// ---------------------------------------------------------------------------
// Seq_HyGAN round 3: algebraic folding.
//   stage2 logit: dot(k_v[n],q_e[m]) = feat_v[n]·qt_e[m] + c_e[m]
//     qt_e = feat_e@(W1@W2^T) + W2@b1 ;  c_e[m] = feat_e[m]·(W1@b2) + b1·b2
//   stage2 output: feat_e2 = agg@W3 + flag*b3  (softmax weights sum to 1)
//     pred = agg@(W3@Wc) + flag*(b3@Wc) + bc   -> W3 folded into head
//   => stage-2 gathers ONE feat_v row per edge (was k_v+v_v = 2 rows),
//      and the two N-row GEMMs (W2,W3) are eliminated.
// ---------------------------------------------------------------------------

#define HY_M 10000
#define HY_N 100000
#define HY_E 640000

// ---------------- small utility kernels ----------------
__global__ void zero_ints(int* __restrict__ p, int n) {
    int i = blockIdx.x * blockDim.x + threadIdx.x;
    if (i < n) p[i] = 0;
}

__global__ void fillk(float* __restrict__ p, float v, int n) {
    int stride = gridDim.x * blockDim.x;
    for (int i = blockIdx.x * blockDim.x + threadIdx.x; i < n; i += stride) p[i] = v;
}

__global__ void hist_kernel(const int* __restrict__ dst, int* __restrict__ cnt, int E) {
    int e = blockIdx.x * blockDim.x + threadIdx.x;
    if (e < E) atomicAdd(&cnt[dst[e]], 1);
}

__global__ void scanA(const int* __restrict__ cnt, int* __restrict__ bsum, int n) {
    __shared__ int s[256];
    int t = threadIdx.x, base = blockIdx.x * 1024;
    int v = 0;
    for (int i = t; i < 1024; i += 256) { int g = base + i; if (g < n) v += cnt[g]; }
    s[t] = v; __syncthreads();
    for (int off = 128; off; off >>= 1) { if (t < off) s[t] += s[t + off]; __syncthreads(); }
    if (t == 0) bsum[blockIdx.x] = s[0];
}

__global__ void scanB(int* __restrict__ bsum, int nb) {   // single block, nb<=256
    __shared__ int s[256];
    int t = threadIdx.x;
    int orig = (t < nb) ? bsum[t] : 0;
    s[t] = orig; __syncthreads();
    for (int off = 1; off < 256; off <<= 1) {
        int v = (t >= off) ? s[t - off] : 0;
        __syncthreads(); s[t] += v; __syncthreads();
    }
    if (t < nb) bsum[t] = s[t] - orig;  // exclusive
}

__global__ void scanC(const int* __restrict__ cnt, const int* __restrict__ bsum,
                      int* __restrict__ off, int n, int total) {
    __shared__ int s[256];
    int t = threadIdx.x, base = blockIdx.x * 1024;
    int idx = base + t * 4;
    int v[4], sum = 0;
    #pragma unroll
    for (int j = 0; j < 4; ++j) { v[j] = (idx + j < n) ? cnt[idx + j] : 0; sum += v[j]; }
    int orig = sum;
    s[t] = sum; __syncthreads();
    for (int o = 1; o < 256; o <<= 1) {
        int x = (t >= o) ? s[t - o] : 0;
        __syncthreads(); s[t] += x; __syncthreads();
    }
    int excl = s[t] - orig + bsum[blockIdx.x];
    #pragma unroll
    for (int j = 0; j < 4; ++j) { if (idx + j < n) off[idx + j] = excl; excl += v[j]; }
    if (blockIdx.x == 0 && t == 0) off[n] = total;
}

// store the OTHER endpoint (src) directly -> no per-edge double indirection later
__global__ void fill_csr_src(const int* __restrict__ dst, const int* __restrict__ srcv,
                             const int* __restrict__ off, int* __restrict__ cursor,
                             int* __restrict__ adj, int E) {
    int e = blockIdx.x * blockDim.x + threadIdx.x;
    if (e >= E) return;
    int d = dst[e];
    int p = atomicAdd(&cursor[d], 1);
    adj[off[d] + p] = srcv[e];
}

// ---------------- dense f32 GEMM, fixed K=N=128, 64-row tiles ----------------
__launch_bounds__(512)
__global__ void gemm128(const float* __restrict__ A, const float* __restrict__ W,
                        const float* __restrict__ b, float* __restrict__ C, int nrows) {
    __shared__ __align__(16) float wlds[128 * 128];   // 64 KB
    __shared__ __align__(16) float at[128 * 68];      // transposed A tile, padded
    const int tid = threadIdx.x;
    {
        const float4* src = (const float4*)W;
        float4* dst = (float4*)wlds;
        for (int i = tid; i < 128 * 128 / 4; i += 512) dst[i] = src[i];
    }
    const int rowbase = blockIdx.x * 64;
    for (int i = tid; i < 64 * 128; i += 512) {
        int r = i >> 7, k = i & 127;
        int gr = rowbase + r;
        at[k * 68 + r] = (gr < nrows) ? A[(size_t)gr * 128 + k] : 0.f;
    }
    __syncthreads();
    const int cg = tid & 31;
    const int rs = tid >> 5;
    float acc[4][4] = {};
    #pragma unroll 4
    for (int k = 0; k < 128; ++k) {
        const float4 av = *(const float4*)&at[k * 68 + rs * 4];
        const float4 wv = *(const float4*)&wlds[k * 128 + cg * 4];
        float a4[4] = {av.x, av.y, av.z, av.w};
        float w4[4] = {wv.x, wv.y, wv.z, wv.w};
        #pragma unroll
        for (int r = 0; r < 4; ++r)
            #pragma unroll
            for (int c = 0; c < 4; ++c)
                acc[r][c] = fmaf(a4[r], w4[c], acc[r][c]);
    }
    const float4 bv = *(const float4*)&b[cg * 4];
    #pragma unroll
    for (int r = 0; r < 4; ++r) {
        int gr = rowbase + rs * 4 + r;
        if (gr < nrows) {
            float4 o = {acc[r][0] + bv.x, acc[r][1] + bv.y,
                        acc[r][2] + bv.z, acc[r][3] + bv.w};
            *(float4*)&C[(size_t)gr * 128 + cg * 4] = o;
        }
    }
}

// ---------------- tiny precompute kernels ----------------
__global__ void transpose128(const float* __restrict__ W, float* __restrict__ WT) {
    int i = blockIdx.x * 256 + threadIdx.x;   // 64 blocks
    if (i < 128 * 128) WT[(i & 127) * 128 + (i >> 7)] = W[i];
}

// b12 = W2@b1 ; w1b2 = W1@b2 ; s12 = b1.b2
__global__ void prep_vecs(const float* __restrict__ W1, const float* __restrict__ W2,
                          const float* __restrict__ b1, const float* __restrict__ b2,
                          float* __restrict__ b12, float* __restrict__ w1b2,
                          float* __restrict__ s12) {
    int t = threadIdx.x;  // 256
    if (t < 128) {
        float acc = 0.f;
        for (int j = 0; j < 128; ++j) acc += W2[t * 128 + j] * b1[j];
        b12[t] = acc;
    } else {
        int k = t - 128;
        float acc = 0.f;
        for (int j = 0; j < 128; ++j) acc += W1[k * 128 + j] * b2[j];
        w1b2[k] = acc;
    }
    if (t == 0) {
        float acc = 0.f;
        for (int j = 0; j < 128; ++j) acc += b1[j] * b2[j];
        *s12 = acc;
    }
}

// W3c = W3@Wc [128,10] ; b3c = b3@Wc [10]
__global__ void prep_w3c(const float* __restrict__ W3, const float* __restrict__ Wc,
                         const float* __restrict__ b3, float* __restrict__ W3c,
                         float* __restrict__ b3c) {
    int i = blockIdx.x * 256 + threadIdx.x;
    if (i < 1280) {
        int k = i / 10, c = i % 10;
        float acc = 0.f;
        for (int j = 0; j < 128; ++j) acc += W3[k * 128 + j] * Wc[j * 10 + c];
        W3c[i] = acc;
    } else if (i < 1290) {
        int c = i - 1280;
        float acc = 0.f;
        for (int j = 0; j < 128; ++j) acc += b3[j] * Wc[j * 10 + c];
        b3c[c] = acc;
    }
}

// c_e[m] = feat_e[m].w1b2 + s12   (one wave per row)
__launch_bounds__(256)
__global__ void dotc(const float* __restrict__ X, const float* __restrict__ w1b2,
                     const float* __restrict__ s12, float* __restrict__ c_e, int M) {
    int w = (blockIdx.x * blockDim.x + threadIdx.x) >> 6;
    int lane = threadIdx.x & 63;
    if (w >= M) return;
    float2 r = ((const float2*)(X + (size_t)w * 128))[lane];
    float2 u = ((const float2*)w1b2)[lane];
    float d = r.x * u.x + r.y * u.y;
    #pragma unroll
    for (int o = 32; o; o >>= 1) d += __shfl_xor(d, o, 64);
    if (lane == 0) c_e[w] = d + *s12;
}

// ---------------- fused attention, stage 1 (dest=node) ----------------
// out[seg] = sum softmax(leaky(K[src].Q[seg])*scale) * V[src]
__launch_bounds__(256)
__global__ void attn_s1(const float* __restrict__ Q, const float* __restrict__ K,
                        const float* __restrict__ V, const int* __restrict__ off,
                        const int* __restrict__ adj, float* __restrict__ outp,
                        int nseg, float scale) {
    int seg = (blockIdx.x * blockDim.x + threadIdx.x) >> 6;
    int lane = threadIdx.x & 63;
    if (seg >= nseg) return;
    int beg = off[seg], end = off[seg + 1];
    float2 q = ((const float2*)(Q + (size_t)seg * 128))[lane];
    float m = -INFINITY, l = 0.f;
    float2 a = {0.f, 0.f};
    for (int i = beg; i < end; ++i) {
        int s = adj[i];
        float2 kr = ((const float2*)(K + (size_t)s * 128))[lane];
        float2 vr = ((const float2*)(V + (size_t)s * 128))[lane];
        float d = kr.x * q.x + kr.y * q.y;
        #pragma unroll
        for (int o = 32; o; o >>= 1) d += __shfl_xor(d, o, 64);
        d = (d >= 0.f ? d : 0.01f * d) * scale;
        if (d <= m) {                        // wave-uniform branch (d uniform)
            float p = __expf(d - m);
            l += p; a.x += p * vr.x; a.y += p * vr.y;
        } else {
            float r = __expf(m - d);         // first iter: exp(-inf)=0
            l = l * r + 1.f;
            a.x = a.x * r + vr.x; a.y = a.y * r + vr.y;
            m = d;
        }
    }
    float inv = (l > 0.f) ? 1.f / l : 0.f;
    ((float2*)(outp + (size_t)seg * 128))[lane] = make_float2(a.x * inv, a.y * inv);
}

// ---------------- fused attention, stage 2 (dest=hyperedge) ----------------
// single gathered table T=feat_v used for BOTH logit and accumulation.
__launch_bounds__(256)
__global__ void attn_s2(const float* __restrict__ QT, const float* __restrict__ cvec,
                        const float* __restrict__ T, const int* __restrict__ off,
                        const int* __restrict__ adj, float* __restrict__ agg,
                        float* __restrict__ flag, int nseg, float scale) {
    int seg = (blockIdx.x * blockDim.x + threadIdx.x) >> 6;
    int lane = threadIdx.x & 63;
    if (seg >= nseg) return;
    int beg = off[seg], end = off[seg + 1];
    float2 q = ((const float2*)(QT + (size_t)seg * 128))[lane];
    float cadd = cvec[seg];
    float m = -INFINITY, l = 0.f;
    float2 a = {0.f, 0.f};
    for (int i = beg; i < end; ++i) {
        int s = adj[i];
        float2 row = ((const float2*)(T + (size_t)s * 128))[lane];
        float d = row.x * q.x + row.y * q.y;
        #pragma unroll
        for (int o = 32; o; o >>= 1) d += __shfl_xor(d, o, 64);
        d += cadd;
        d = (d >= 0.f ? d : 0.01f * d) * scale;
        if (d <= m) {
            float p = __expf(d - m);
            l += p; a.x += p * row.x; a.y += p * row.y;
        } else {
            float r = __expf(m - d);
            l = l * r + 1.f;
            a.x = a.x * r + row.x; a.y = a.y * r + row.y;
            m = d;
        }
    }
    float inv = (l > 0.f) ? 1.f / l : 0.f;
    ((float2*)(agg + (size_t)seg * 128))[lane] = make_float2(a.x * inv, a.y * inv);
    if (lane == 0) flag[seg] = (l > 0.f) ? 1.f : 0.f;
}

// pred[m,c] = agg[m].W3c[:,c] + flag[m]*b3c[c] + bc[c]
__global__ void head2(const float* __restrict__ agg, const float* __restrict__ flag,
                      const float* __restrict__ W3c, const float* __restrict__ b3c,
                      const float* __restrict__ bc, float* __restrict__ out, int M) {
    int t = blockIdx.x * blockDim.x + threadIdx.x;
    if (t >= M * 10) return;
    int row = t / 10, c = t % 10;
    float acc = bc[c] + flag[row] * b3c[c];
    #pragma unroll 8
    for (int k = 0; k < 128; ++k)
        acc = fmaf(agg[(size_t)row * 128 + k], W3c[k * 10 + c], acc);
    out[t] = acc;
}

extern "C" void kernel_launch(void* const* d_in, const int* in_sizes, int n_in,
                              void* d_out, int out_size, void* d_ws, size_t ws_size,
                              hipStream_t stream) {
    const float* vfeat = (const float*)d_in[0];
    const float* efeat = (const float*)d_in[1];
    const int*   he    = (const int*)d_in[2];
    const int*   nd    = (const int*)d_in[3];
    const float* Wfl = (const float*)d_in[6],  *bfl = (const float*)d_in[7];
    const float* W1  = (const float*)d_in[8],  *b1  = (const float*)d_in[9];
    const float* W2  = (const float*)d_in[10], *b2  = (const float*)d_in[11];
    const float* W3  = (const float*)d_in[12], *b3  = (const float*)d_in[13];
    const float* W4  = (const float*)d_in[14], *b4  = (const float*)d_in[15];
    const float* W5  = (const float*)d_in[16], *b5  = (const float*)d_in[17];
    const float* W6  = (const float*)d_in[18], *b6  = (const float*)d_in[19];
    const float* Wc  = (const float*)d_in[20], *bc  = (const float*)d_in[21];
    float* out = (float*)d_out;
    float* ws  = (float*)d_ws;

    const int M = HY_M, N = HY_N, E = HY_E;

    // -------- workspace layout (floats), total ~33.5M = 134 MB --------
    float* q_v    = ws + 0;           // 12.8M
    float* feat_v = ws + 12800000;    // 12.8M  (CSR int scratch overlays: dead till attn_s1)
    float* feat_e = ws + 25600000;    // 1.28M
    float* k_e    = ws + 26880000;    // 1.28M
    float* v_e    = ws + 28160000;    // 1.28M
    float* qt_e   = ws + 29440000;    // 1.28M
    float* agg    = ws + 30720000;    // 1.28M
    float* c_e    = ws + 32000000;    // 10K
    float* flag   = ws + 32010000;    // 10K
    float* W2T    = ws + 32020000;    // 16384
    float* W12    = ws + 32036384;    // 16384
    float* W3c    = ws + 32052768;    // 1280
    float* b3c    = ws + 32054048;    // 16
    float* b12    = ws + 32054064;    // 128
    float* w1b2   = ws + 32054192;    // 128
    float* s12    = ws + 32054320;    // 4
    float* zeros  = ws + 32054324;    // 128
    int* nd_off   = (int*)(ws + 32054456);   // 100001
    int* he_off   = nd_off + 100001;         // 10001
    int* nd_adj   = he_off + 10001;          // 640000 (stores he[e])
    int* he_adj   = nd_adj + 640000;         // 640000 (stores nd[e])
    int* cnt      = (int*)feat_v;            // 100000 (overlay)
    int* cursor   = cnt + 100000;            // 100000
    int* bsum     = cursor + 100000;         // 128

    const float scale = 0.08838834764831843f;  // 1/sqrt(128)

    // -------- CSR builds --------
    {   // by node (stage 1): adj stores hyperedge index
        int nb = (N + 1023) / 1024;
        zero_ints<<<(N + 255) / 256, 256, 0, stream>>>(cnt, N);
        hist_kernel<<<(E + 255) / 256, 256, 0, stream>>>(nd, cnt, E);
        scanA<<<nb, 256, 0, stream>>>(cnt, bsum, N);
        scanB<<<1, 256, 0, stream>>>(bsum, nb);
        scanC<<<nb, 256, 0, stream>>>(cnt, bsum, nd_off, N, E);
        zero_ints<<<(N + 255) / 256, 256, 0, stream>>>(cursor, N);
        fill_csr_src<<<(E + 255) / 256, 256, 0, stream>>>(nd, he, nd_off, cursor, nd_adj, E);
    }
    {   // by hyperedge (stage 2): adj stores node index
        int nb = (M + 1023) / 1024;
        zero_ints<<<(M + 255) / 256, 256, 0, stream>>>(cnt, M);
        hist_kernel<<<(E + 255) / 256, 256, 0, stream>>>(he, cnt, E);
        scanA<<<nb, 256, 0, stream>>>(cnt, bsum, M);
        scanB<<<1, 256, 0, stream>>>(bsum, nb);
        scanC<<<nb, 256, 0, stream>>>(cnt, bsum, he_off, M, E);
        zero_ints<<<(M + 255) / 256, 256, 0, stream>>>(cursor, M);
        fill_csr_src<<<(E + 255) / 256, 256, 0, stream>>>(he, nd, he_off, cursor, he_adj, E);
    }

    // -------- weight precomputes --------
    transpose128<<<64, 256, 0, stream>>>(W2, W2T);
    fillk<<<1, 128, 0, stream>>>(zeros, 0.f, 128);
    prep_vecs<<<1, 256, 0, stream>>>(W1, W2, b1, b2, b12, w1b2, s12);
    gemm128<<<2, 512, 0, stream>>>(W1, W2T, zeros, W12, 128);       // W12 = W1@W2^T
    prep_w3c<<<6, 256, 0, stream>>>(W3, Wc, b3, W3c, b3c);

    // -------- dense layers --------
    gemm128<<<(M + 63) / 64, 512, 0, stream>>>(efeat, Wfl, bfl, feat_e, M);
    gemm128<<<(M + 63) / 64, 512, 0, stream>>>(feat_e, W5, b5, k_e, M);
    gemm128<<<(M + 63) / 64, 512, 0, stream>>>(feat_e, W6, b6, v_e, M);
    gemm128<<<(M + 63) / 64, 512, 0, stream>>>(feat_e, W12, b12, qt_e, M);
    dotc<<<(M * 64 + 255) / 256, 256, 0, stream>>>(feat_e, w1b2, s12, c_e, M);
    gemm128<<<(N + 63) / 64, 512, 0, stream>>>(vfeat, W4, b4, q_v, N);

    // -------- stage 1: hyperedge -> node --------
    attn_s1<<<(N * 64 + 255) / 256, 256, 0, stream>>>(
        q_v, k_e, v_e, nd_off, nd_adj, feat_v, N, scale);

    // -------- stage 2: node -> hyperedge (single-table gather) --------
    attn_s2<<<(M * 64 + 255) / 256, 256, 0, stream>>>(
        qt_e, c_e, feat_v, he_off, he_adj, agg, flag, M, scale);

    // -------- head: pred = agg@W3c + flag*b3c + bc --------
    head2<<<(M * 10 + 255) / 256, 256, 0, stream>>>(agg, flag, W3c, b3c, bc, out, M);
}

// Round 4
// 506.985 us; speedup vs baseline: 2.4365x; 1.1569x over previous
//
#include <hip/hip_runtime.h>
#include <hip/hip_bf16.h>
#include <math.h>

// ---------------------------------------------------------------------------
// Seq_HyGAN round 4:
//  * gemm128: W-only LDS (64KB -> 2 blocks/CU), A read via wave-broadcast
//    global loads (no LDS A-tile, no 8-way-conflict transpose store).
//  * 3 feat_e GEMMs batched into one launch (blockIdx.y picks weights).
//  * attn_s2: one 4-wave block per segment (4x parallelism, serial chain /4)
//    + one-ahead prefetch; LDS merge of partial online-softmax states.
//  * attn_s1: one-ahead prefetch pipeline.
//  * CSR build: fused dual histogram + fused dual fill.
// ---------------------------------------------------------------------------

#define HY_M 10000
#define HY_N 100000
#define HY_E 640000

// ---------------- small utility kernels ----------------
__global__ void zero_ints(int* __restrict__ p, int n) {
    int i = blockIdx.x * blockDim.x + threadIdx.x;
    if (i < n) p[i] = 0;
}

__global__ void fillk(float* __restrict__ p, float v, int n) {
    int stride = gridDim.x * blockDim.x;
    for (int i = blockIdx.x * blockDim.x + threadIdx.x; i < n; i += stride) p[i] = v;
}

__global__ void hist2(const int* __restrict__ nd, const int* __restrict__ he,
                      int* __restrict__ ncnt, int* __restrict__ hcnt, int E) {
    int e = blockIdx.x * blockDim.x + threadIdx.x;
    if (e < E) { atomicAdd(&ncnt[nd[e]], 1); atomicAdd(&hcnt[he[e]], 1); }
}

__global__ void scanA(const int* __restrict__ cnt, int* __restrict__ bsum, int n) {
    __shared__ int s[256];
    int t = threadIdx.x, base = blockIdx.x * 1024;
    int v = 0;
    for (int i = t; i < 1024; i += 256) { int g = base + i; if (g < n) v += cnt[g]; }
    s[t] = v; __syncthreads();
    for (int off = 128; off; off >>= 1) { if (t < off) s[t] += s[t + off]; __syncthreads(); }
    if (t == 0) bsum[blockIdx.x] = s[0];
}

__global__ void scanB(int* __restrict__ bsum, int nb) {   // single block, nb<=256
    __shared__ int s[256];
    int t = threadIdx.x;
    int orig = (t < nb) ? bsum[t] : 0;
    s[t] = orig; __syncthreads();
    for (int off = 1; off < 256; off <<= 1) {
        int v = (t >= off) ? s[t - off] : 0;
        __syncthreads(); s[t] += v; __syncthreads();
    }
    if (t < nb) bsum[t] = s[t] - orig;  // exclusive
}

__global__ void scanC(const int* __restrict__ cnt, const int* __restrict__ bsum,
                      int* __restrict__ off, int n, int total) {
    __shared__ int s[256];
    int t = threadIdx.x, base = blockIdx.x * 1024;
    int idx = base + t * 4;
    int v[4], sum = 0;
    #pragma unroll
    for (int j = 0; j < 4; ++j) { v[j] = (idx + j < n) ? cnt[idx + j] : 0; sum += v[j]; }
    int orig = sum;
    s[t] = sum; __syncthreads();
    for (int o = 1; o < 256; o <<= 1) {
        int x = (t >= o) ? s[t - o] : 0;
        __syncthreads(); s[t] += x; __syncthreads();
    }
    int excl = s[t] - orig + bsum[blockIdx.x];
    #pragma unroll
    for (int j = 0; j < 4; ++j) { if (idx + j < n) off[idx + j] = excl; excl += v[j]; }
    if (blockIdx.x == 0 && t == 0) off[n] = total;
}

__global__ void fill2(const int* __restrict__ nd, const int* __restrict__ he,
                      const int* __restrict__ noff, const int* __restrict__ hoff,
                      int* __restrict__ ncur, int* __restrict__ hcur,
                      int* __restrict__ nadj, int* __restrict__ hadj, int E) {
    int e = blockIdx.x * blockDim.x + threadIdx.x;
    if (e >= E) return;
    int d = nd[e], h = he[e];
    nadj[noff[d] + atomicAdd(&ncur[d], 1)] = h;
    hadj[hoff[h] + atomicAdd(&hcur[h], 1)] = d;
}

// ---------------- dense f32 GEMM: K=N=128, 64-row tiles, W-only LDS ----------
__device__ __forceinline__ void gemm_body(const float* __restrict__ A,
        const float* __restrict__ W, const float* __restrict__ b,
        float* __restrict__ C, int nrows, float* wlds) {
    const int tid = threadIdx.x;
    for (int i = tid; i < 4096; i += 512)
        ((float4*)wlds)[i] = ((const float4*)W)[i];
    __syncthreads();
    const int cg = tid & 31;          // cols 4cg..4cg+3
    const int rs = tid >> 5;          // row group 0..15
    const int row0 = blockIdx.x * 64 + rs * 4;
    // clamp rows (tail): compute garbage, store guarded
    const float4* A0 = (const float4*)(A + (size_t)min(row0 + 0, nrows - 1) * 128);
    const float4* A1 = (const float4*)(A + (size_t)min(row0 + 1, nrows - 1) * 128);
    const float4* A2 = (const float4*)(A + (size_t)min(row0 + 2, nrows - 1) * 128);
    const float4* A3 = (const float4*)(A + (size_t)min(row0 + 3, nrows - 1) * 128);
    float acc[4][4] = {};
    #pragma unroll 2
    for (int kq = 0; kq < 32; ++kq) {
        float4 ar[4] = {A0[kq], A1[kq], A2[kq], A3[kq]};    // wave-broadcast loads
        const float4* wk = (const float4*)(wlds + kq * 512);
        float4 wr[4] = {wk[cg], wk[32 + cg], wk[64 + cg], wk[96 + cg]};
        #pragma unroll
        for (int r = 0; r < 4; ++r) {
            float av[4] = {ar[r].x, ar[r].y, ar[r].z, ar[r].w};
            #pragma unroll
            for (int j = 0; j < 4; ++j) {
                float wv[4] = {wr[j].x, wr[j].y, wr[j].z, wr[j].w};
                #pragma unroll
                for (int c = 0; c < 4; ++c)
                    acc[r][c] = fmaf(av[j], wv[c], acc[r][c]);
            }
        }
    }
    const float4 bv = ((const float4*)b)[cg];
    #pragma unroll
    for (int r = 0; r < 4; ++r) {
        int gr = row0 + r;
        if (gr < nrows) {
            float4 o = {acc[r][0] + bv.x, acc[r][1] + bv.y,
                        acc[r][2] + bv.z, acc[r][3] + bv.w};
            ((float4*)(C + (size_t)gr * 128))[cg] = o;
        }
    }
}

__launch_bounds__(512)
__global__ void gemm128(const float* __restrict__ A, const float* __restrict__ W,
                        const float* __restrict__ b, float* __restrict__ C, int nrows) {
    __shared__ __align__(16) float wlds[16384];
    gemm_body(A, W, b, C, nrows, wlds);
}

__launch_bounds__(512)
__global__ void gemm128x3(const float* __restrict__ A,
        const float* __restrict__ Wa, const float* __restrict__ ba, float* __restrict__ Ca,
        const float* __restrict__ Wb, const float* __restrict__ bb, float* __restrict__ Cb,
        const float* __restrict__ Wd, const float* __restrict__ bd, float* __restrict__ Cd,
        int nrows) {
    __shared__ __align__(16) float wlds[16384];
    const float* W = blockIdx.y == 0 ? Wa : (blockIdx.y == 1 ? Wb : Wd);
    const float* b = blockIdx.y == 0 ? ba : (blockIdx.y == 1 ? bb : bd);
    float*       C = blockIdx.y == 0 ? Ca : (blockIdx.y == 1 ? Cb : Cd);
    gemm_body(A, W, b, C, nrows, wlds);
}

// ---------------- tiny precompute kernels ----------------
__global__ void transpose128(const float* __restrict__ W, float* __restrict__ WT) {
    int i = blockIdx.x * 256 + threadIdx.x;   // 64 blocks
    if (i < 128 * 128) WT[(i & 127) * 128 + (i >> 7)] = W[i];
}

__global__ void prep_vecs(const float* __restrict__ W1, const float* __restrict__ W2,
                          const float* __restrict__ b1, const float* __restrict__ b2,
                          float* __restrict__ b12, float* __restrict__ w1b2,
                          float* __restrict__ s12) {
    int t = threadIdx.x;  // 256
    if (t < 128) {
        float acc = 0.f;
        for (int j = 0; j < 128; ++j) acc += W2[t * 128 + j] * b1[j];
        b12[t] = acc;
    } else {
        int k = t - 128;
        float acc = 0.f;
        for (int j = 0; j < 128; ++j) acc += W1[k * 128 + j] * b2[j];
        w1b2[k] = acc;
    }
    if (t == 0) {
        float acc = 0.f;
        for (int j = 0; j < 128; ++j) acc += b1[j] * b2[j];
        *s12 = acc;
    }
}

__global__ void prep_w3c(const float* __restrict__ W3, const float* __restrict__ Wc,
                         const float* __restrict__ b3, float* __restrict__ W3c,
                         float* __restrict__ b3c) {
    int i = blockIdx.x * 256 + threadIdx.x;
    if (i < 1280) {
        int k = i / 10, c = i % 10;
        float acc = 0.f;
        for (int j = 0; j < 128; ++j) acc += W3[k * 128 + j] * Wc[j * 10 + c];
        W3c[i] = acc;
    } else if (i < 1290) {
        int c = i - 1280;
        float acc = 0.f;
        for (int j = 0; j < 128; ++j) acc += b3[j] * Wc[j * 10 + c];
        b3c[c] = acc;
    }
}

// c_e[m] = feat_e[m].w1b2 + s12   (one wave per row)
__launch_bounds__(256)
__global__ void dotc(const float* __restrict__ X, const float* __restrict__ w1b2,
                     const float* __restrict__ s12, float* __restrict__ c_e, int M) {
    int w = (blockIdx.x * blockDim.x + threadIdx.x) >> 6;
    int lane = threadIdx.x & 63;
    if (w >= M) return;
    float2 r = ((const float2*)(X + (size_t)w * 128))[lane];
    float2 u = ((const float2*)w1b2)[lane];
    float d = r.x * u.x + r.y * u.y;
    #pragma unroll
    for (int o = 32; o; o >>= 1) d += __shfl_xor(d, o, 64);
    if (lane == 0) c_e[w] = d + *s12;
}

// ---------------- fused attention, stage 1 (dest=node, 1 wave/segment) -------
__launch_bounds__(256)
__global__ void attn_s1(const float* __restrict__ Q, const float* __restrict__ K,
                        const float* __restrict__ V, const int* __restrict__ off,
                        const int* __restrict__ adj, float* __restrict__ outp,
                        int nseg, float scale) {
    int seg = (blockIdx.x * blockDim.x + threadIdx.x) >> 6;
    int lane = threadIdx.x & 63;
    if (seg >= nseg) return;
    int beg = off[seg], end = off[seg + 1];
    float2 q = ((const float2*)(Q + (size_t)seg * 128))[lane];
    float m = -INFINITY, l = 0.f;
    float2 a = {0.f, 0.f};
    if (beg < end) {
        int s = adj[beg];
        float2 kr = ((const float2*)(K + (size_t)s * 128))[lane];
        float2 vr = ((const float2*)(V + (size_t)s * 128))[lane];
        for (int i = beg; i < end; ++i) {
            float2 kc = kr, vc = vr;
            if (i + 1 < end) {                     // wave-uniform; prefetch next
                int s2 = adj[i + 1];
                kr = ((const float2*)(K + (size_t)s2 * 128))[lane];
                vr = ((const float2*)(V + (size_t)s2 * 128))[lane];
            }
            float d = kc.x * q.x + kc.y * q.y;
            #pragma unroll
            for (int o = 32; o; o >>= 1) d += __shfl_xor(d, o, 64);
            d = (d >= 0.f ? d : 0.01f * d) * scale;
            if (d <= m) {
                float p = __expf(d - m);
                l += p; a.x += p * vc.x; a.y += p * vc.y;
            } else {
                float r = __expf(m - d);           // first iter: exp(-inf)=0
                l = l * r + 1.f;
                a.x = a.x * r + vc.x; a.y = a.y * r + vc.y;
                m = d;
            }
        }
    }
    float inv = (l > 0.f) ? 1.f / l : 0.f;
    ((float2*)(outp + (size_t)seg * 128))[lane] = make_float2(a.x * inv, a.y * inv);
}

// ---------------- fused attention, stage 2 (dest=hyperedge) ------------------
// one 4-wave block per segment; partial online softmax per wave, LDS merge.
__launch_bounds__(256)
__global__ void attn_s2(const float* __restrict__ QT, const float* __restrict__ cvec,
                        const float* __restrict__ T, const int* __restrict__ off,
                        const int* __restrict__ adj, float* __restrict__ agg,
                        float* __restrict__ flag, float scale) {
    __shared__ float sm[4], sl[4];
    __shared__ float2 sa[4][64];
    const int seg = blockIdx.x;
    const int wid = threadIdx.x >> 6, lane = threadIdx.x & 63;
    const int beg = off[seg], end = off[seg + 1];
    const float2 q = ((const float2*)(QT + (size_t)seg * 128))[lane];
    const float cadd = cvec[seg];
    float m = -INFINITY, l = 0.f;
    float2 a = {0.f, 0.f};
    int i = beg + wid;
    if (i < end) {
        int s = adj[i];
        float2 row = ((const float2*)(T + (size_t)s * 128))[lane];
        for (; i < end; i += 4) {
            float2 cur = row;
            if (i + 4 < end) {                     // wave-uniform prefetch
                int s2 = adj[i + 4];
                row = ((const float2*)(T + (size_t)s2 * 128))[lane];
            }
            float d = cur.x * q.x + cur.y * q.y;
            #pragma unroll
            for (int o = 32; o; o >>= 1) d += __shfl_xor(d, o, 64);
            d += cadd;
            d = (d >= 0.f ? d : 0.01f * d) * scale;
            if (d <= m) {
                float p = __expf(d - m);
                l += p; a.x += p * cur.x; a.y += p * cur.y;
            } else {
                float r = __expf(m - d);
                l = l * r + 1.f;
                a.x = a.x * r + cur.x; a.y = a.y * r + cur.y;
                m = d;
            }
        }
    }
    if (lane == 0) { sm[wid] = m; sl[wid] = l; }
    sa[wid][lane] = a;
    __syncthreads();
    if (wid == 0) {
        float M2 = fmaxf(fmaxf(sm[0], sm[1]), fmaxf(sm[2], sm[3]));
        float L = 0.f;
        float2 acc = {0.f, 0.f};
        #pragma unroll
        for (int w = 0; w < 4; ++w) {
            float f = (sl[w] > 0.f) ? __expf(sm[w] - M2) : 0.f;  // guard all-empty NaN
            L += f * sl[w];
            float2 v = sa[w][lane];
            acc.x += f * v.x; acc.y += f * v.y;
        }
        float inv = (L > 0.f) ? 1.f / L : 0.f;
        ((float2*)(agg + (size_t)seg * 128))[lane] = make_float2(acc.x * inv, acc.y * inv);
        if (lane == 0) flag[seg] = (L > 0.f) ? 1.f : 0.f;
    }
}

// pred[m,c] = agg[m].W3c[:,c] + flag[m]*b3c[c] + bc[c]
__global__ void head2(const float* __restrict__ agg, const float* __restrict__ flag,
                      const float* __restrict__ W3c, const float* __restrict__ b3c,
                      const float* __restrict__ bc, float* __restrict__ out, int M) {
    int t = blockIdx.x * blockDim.x + threadIdx.x;
    if (t >= M * 10) return;
    int row = t / 10, c = t % 10;
    float acc = bc[c] + flag[row] * b3c[c];
    #pragma unroll 8
    for (int k = 0; k < 128; ++k)
        acc = fmaf(agg[(size_t)row * 128 + k], W3c[k * 10 + c], acc);
    out[t] = acc;
}

extern "C" void kernel_launch(void* const* d_in, const int* in_sizes, int n_in,
                              void* d_out, int out_size, void* d_ws, size_t ws_size,
                              hipStream_t stream) {
    const float* vfeat = (const float*)d_in[0];
    const float* efeat = (const float*)d_in[1];
    const int*   he    = (const int*)d_in[2];
    const int*   nd    = (const int*)d_in[3];
    const float* Wfl = (const float*)d_in[6],  *bfl = (const float*)d_in[7];
    const float* W1  = (const float*)d_in[8],  *b1  = (const float*)d_in[9];
    const float* W2  = (const float*)d_in[10], *b2  = (const float*)d_in[11];
    const float* W3  = (const float*)d_in[12], *b3  = (const float*)d_in[13];
    const float* W4  = (const float*)d_in[14], *b4  = (const float*)d_in[15];
    const float* W5  = (const float*)d_in[16], *b5  = (const float*)d_in[17];
    const float* W6  = (const float*)d_in[18], *b6  = (const float*)d_in[19];
    const float* Wc  = (const float*)d_in[20], *bc  = (const float*)d_in[21];
    float* out = (float*)d_out;
    float* ws  = (float*)d_ws;

    const int M = HY_M, N = HY_N, E = HY_E;

    // -------- workspace layout (floats) --------
    float* q_v    = ws + 0;           // 12.8M
    float* feat_v = ws + 12800000;    // 12.8M  (CSR int scratch overlay: dead till attn_s1)
    float* feat_e = ws + 25600000;    // 1.28M
    float* k_e    = ws + 26880000;    // 1.28M
    float* v_e    = ws + 28160000;    // 1.28M
    float* qt_e   = ws + 29440000;    // 1.28M
    float* agg    = ws + 30720000;    // 1.28M
    float* c_e    = ws + 32000000;    // 10K
    float* flag   = ws + 32010000;    // 10K
    float* W2T    = ws + 32020000;    // 16384
    float* W12    = ws + 32036384;    // 16384
    float* W3c    = ws + 32052768;    // 1280
    float* b3c    = ws + 32054048;    // 16
    float* b12    = ws + 32054064;    // 128
    float* w1b2   = ws + 32054192;    // 128
    float* s12    = ws + 32054320;    // 4
    float* zeros  = ws + 32054324;    // 128
    int* nd_off   = (int*)(ws + 32054456);   // 100001
    int* he_off   = nd_off + 100001;         // 10001
    int* nd_adj   = he_off + 10001;          // 640000 (stores he[e])
    int* he_adj   = nd_adj + 640000;         // 640000 (stores nd[e])
    // CSR-build scratch overlay on feat_v (dead until attn_s1 writes it)
    int* ncnt = (int*)feat_v;                // N
    int* ncur = ncnt + N;                    // N
    int* hcnt = ncur + N;                    // M
    int* hcur = hcnt + M;                    // M
    int* bsN  = hcur + M;                    // 128
    int* bsM  = bsN + 128;                   // 128

    const float scale = 0.08838834764831843f;  // 1/sqrt(128)

    // -------- CSR builds (both orientations) --------
    zero_ints<<<(2 * N + 2 * M + 255) / 256, 256, 0, stream>>>(ncnt, 2 * N + 2 * M);
    hist2<<<(E + 255) / 256, 256, 0, stream>>>(nd, he, ncnt, hcnt, E);
    {
        int nbN = (N + 1023) / 1024, nbM = (M + 1023) / 1024;
        scanA<<<nbN, 256, 0, stream>>>(ncnt, bsN, N);
        scanB<<<1, 256, 0, stream>>>(bsN, nbN);
        scanC<<<nbN, 256, 0, stream>>>(ncnt, bsN, nd_off, N, E);
        scanA<<<nbM, 256, 0, stream>>>(hcnt, bsM, M);
        scanB<<<1, 256, 0, stream>>>(bsM, nbM);
        scanC<<<nbM, 256, 0, stream>>>(hcnt, bsM, he_off, M, E);
    }
    fill2<<<(E + 255) / 256, 256, 0, stream>>>(nd, he, nd_off, he_off,
                                               ncur, hcur, nd_adj, he_adj, E);

    // -------- weight precomputes --------
    transpose128<<<64, 256, 0, stream>>>(W2, W2T);
    fillk<<<1, 128, 0, stream>>>(zeros, 0.f, 128);
    prep_vecs<<<1, 256, 0, stream>>>(W1, W2, b1, b2, b12, w1b2, s12);
    gemm128<<<2, 512, 0, stream>>>(W1, W2T, zeros, W12, 128);       // W12 = W1@W2^T
    prep_w3c<<<6, 256, 0, stream>>>(W3, Wc, b3, W3c, b3c);

    // -------- dense layers --------
    gemm128<<<(M + 63) / 64, 512, 0, stream>>>(efeat, Wfl, bfl, feat_e, M);
    gemm128x3<<<dim3((M + 63) / 64, 3), 512, 0, stream>>>(
        feat_e, W5, b5, k_e, W6, b6, v_e, W12, b12, qt_e, M);
    dotc<<<(M * 64 + 255) / 256, 256, 0, stream>>>(feat_e, w1b2, s12, c_e, M);
    gemm128<<<(N + 63) / 64, 512, 0, stream>>>(vfeat, W4, b4, q_v, N);

    // -------- stage 1: hyperedge -> node --------
    attn_s1<<<(N * 64 + 255) / 256, 256, 0, stream>>>(
        q_v, k_e, v_e, nd_off, nd_adj, feat_v, N, scale);

    // -------- stage 2: node -> hyperedge (4-wave block per segment) --------
    attn_s2<<<M, 256, 0, stream>>>(qt_e, c_e, feat_v, he_off, he_adj, agg, flag, scale);

    // -------- head --------
    head2<<<(M * 10 + 255) / 256, 256, 0, stream>>>(agg, flag, W3c, b3c, bc, out, M);
}

// Round 5
// 450.992 us; speedup vs baseline: 2.7390x; 1.1242x over previous
//
#include <hip/hip_runtime.h>
#include <hip/hip_bf16.h>
#include <math.h>

// ---------------------------------------------------------------------------
// Seq_HyGAN round 5: bf16 gather tables.
//  * k_e|v_e interleaved bf16 table (2.56 MB -> per-XCD L2 resident),
//    written directly by the batched GEMM epilogue.
//  * q_v stream stored bf16 (halves stage-1 stream + GEMM write).
//  * feat_v stored bf16 by attn_s1 (halves its write + stage-2 gather).
//  All dots/accumulation stay f32. absmax budget: 4.18e-3, expect ~1.5e-3.
// ---------------------------------------------------------------------------

#define HY_M 10000
#define HY_N 100000
#define HY_E 640000

// ---- bf16 helpers (manual, RN) ----
__device__ __forceinline__ unsigned int f2bf(float x) {
    unsigned int u = __float_as_uint(x);
    return (u + 0x7fffu + ((u >> 16) & 1u)) >> 16;
}
__device__ __forceinline__ float2 bf2x2(unsigned int w) {   // elems (2l, 2l+1)
    float lo = __uint_as_float(w << 16);
    float hi = __uint_as_float(w & 0xffff0000u);
    return make_float2(lo, hi);
}

// ---------------- small utility kernels ----------------
__global__ void zero_ints(int* __restrict__ p, int n) {
    int i = blockIdx.x * blockDim.x + threadIdx.x;
    if (i < n) p[i] = 0;
}

__global__ void fillk(float* __restrict__ p, float v, int n) {
    int stride = gridDim.x * blockDim.x;
    for (int i = blockIdx.x * blockDim.x + threadIdx.x; i < n; i += stride) p[i] = v;
}

__global__ void hist2(const int* __restrict__ nd, const int* __restrict__ he,
                      int* __restrict__ ncnt, int* __restrict__ hcnt, int E) {
    int e = blockIdx.x * blockDim.x + threadIdx.x;
    if (e < E) { atomicAdd(&ncnt[nd[e]], 1); atomicAdd(&hcnt[he[e]], 1); }
}

__global__ void scanA(const int* __restrict__ cnt, int* __restrict__ bsum, int n) {
    __shared__ int s[256];
    int t = threadIdx.x, base = blockIdx.x * 1024;
    int v = 0;
    for (int i = t; i < 1024; i += 256) { int g = base + i; if (g < n) v += cnt[g]; }
    s[t] = v; __syncthreads();
    for (int off = 128; off; off >>= 1) { if (t < off) s[t] += s[t + off]; __syncthreads(); }
    if (t == 0) bsum[blockIdx.x] = s[0];
}

__global__ void scanB(int* __restrict__ bsum, int nb) {   // single block, nb<=256
    __shared__ int s[256];
    int t = threadIdx.x;
    int orig = (t < nb) ? bsum[t] : 0;
    s[t] = orig; __syncthreads();
    for (int off = 1; off < 256; off <<= 1) {
        int v = (t >= off) ? s[t - off] : 0;
        __syncthreads(); s[t] += v; __syncthreads();
    }
    if (t < nb) bsum[t] = s[t] - orig;  // exclusive
}

__global__ void scanC(const int* __restrict__ cnt, const int* __restrict__ bsum,
                      int* __restrict__ off, int n, int total) {
    __shared__ int s[256];
    int t = threadIdx.x, base = blockIdx.x * 1024;
    int idx = base + t * 4;
    int v[4], sum = 0;
    #pragma unroll
    for (int j = 0; j < 4; ++j) { v[j] = (idx + j < n) ? cnt[idx + j] : 0; sum += v[j]; }
    int orig = sum;
    s[t] = sum; __syncthreads();
    for (int o = 1; o < 256; o <<= 1) {
        int x = (t >= o) ? s[t - o] : 0;
        __syncthreads(); s[t] += x; __syncthreads();
    }
    int excl = s[t] - orig + bsum[blockIdx.x];
    #pragma unroll
    for (int j = 0; j < 4; ++j) { if (idx + j < n) off[idx + j] = excl; excl += v[j]; }
    if (blockIdx.x == 0 && t == 0) off[n] = total;
}

__global__ void fill2(const int* __restrict__ nd, const int* __restrict__ he,
                      const int* __restrict__ noff, const int* __restrict__ hoff,
                      int* __restrict__ ncur, int* __restrict__ hcur,
                      int* __restrict__ nadj, int* __restrict__ hadj, int E) {
    int e = blockIdx.x * blockDim.x + threadIdx.x;
    if (e >= E) return;
    int d = nd[e], h = he[e];
    nadj[noff[d] + atomicAdd(&ncur[d], 1)] = h;
    hadj[hoff[h] + atomicAdd(&hcur[h], 1)] = d;
}

// ---------------- dense f32 GEMM core: K=N=128, 64-row tiles, W-only LDS -----
__device__ __forceinline__ void gemm_accum(const float* __restrict__ A,
        const float* __restrict__ W, int nrows, float* wlds,
        float (&acc)[4][4], int row0) {
    const int tid = threadIdx.x;
    const int cg = tid & 31;
    for (int i = tid; i < 4096; i += 512)
        ((float4*)wlds)[i] = ((const float4*)W)[i];
    __syncthreads();
    const float4* A0 = (const float4*)(A + (size_t)min(row0 + 0, nrows - 1) * 128);
    const float4* A1 = (const float4*)(A + (size_t)min(row0 + 1, nrows - 1) * 128);
    const float4* A2 = (const float4*)(A + (size_t)min(row0 + 2, nrows - 1) * 128);
    const float4* A3 = (const float4*)(A + (size_t)min(row0 + 3, nrows - 1) * 128);
    #pragma unroll 2
    for (int kq = 0; kq < 32; ++kq) {
        float4 ar[4] = {A0[kq], A1[kq], A2[kq], A3[kq]};    // wave-broadcast loads
        const float4* wk = (const float4*)(wlds + kq * 512);
        float4 wr[4] = {wk[cg], wk[32 + cg], wk[64 + cg], wk[96 + cg]};
        #pragma unroll
        for (int r = 0; r < 4; ++r) {
            float av[4] = {ar[r].x, ar[r].y, ar[r].z, ar[r].w};
            #pragma unroll
            for (int j = 0; j < 4; ++j) {
                float wv[4] = {wr[j].x, wr[j].y, wr[j].z, wr[j].w};
                #pragma unroll
                for (int c = 0; c < 4; ++c)
                    acc[r][c] = fmaf(av[j], wv[c], acc[r][c]);
            }
        }
    }
}

// epilogue: optional f32 store (Cf, row stride 128) and/or bf16 store
// (Cb ushort base, row stride ldb ushorts, column offset coloff).
__device__ __forceinline__ void gemm_epilogue(const float* __restrict__ b,
        float* __restrict__ Cf, unsigned short* __restrict__ Cb, int ldb, int coloff,
        int nrows, float (&acc)[4][4], int row0) {
    const int cg = threadIdx.x & 31;
    const float4 bv = ((const float4*)b)[cg];
    #pragma unroll
    for (int r = 0; r < 4; ++r) {
        int gr = row0 + r;
        if (gr < nrows) {
            float o0 = acc[r][0] + bv.x, o1 = acc[r][1] + bv.y;
            float o2 = acc[r][2] + bv.z, o3 = acc[r][3] + bv.w;
            if (Cf) {
                float4 o = {o0, o1, o2, o3};
                ((float4*)(Cf + (size_t)gr * 128))[cg] = o;
            }
            if (Cb) {
                uint2 pk;
                pk.x = f2bf(o0) | (f2bf(o1) << 16);
                pk.y = f2bf(o2) | (f2bf(o3) << 16);
                *(uint2*)(Cb + (size_t)gr * ldb + coloff + cg * 4) = pk;
            }
        }
    }
}

__launch_bounds__(512)
__global__ void gemm_uni(const float* __restrict__ A, const float* __restrict__ W,
                         const float* __restrict__ b, float* __restrict__ Cf,
                         unsigned short* __restrict__ Cb, int ldb, int coloff, int nrows) {
    __shared__ __align__(16) float wlds[16384];
    const int rs = threadIdx.x >> 5;
    const int row0 = blockIdx.x * 64 + rs * 4;
    float acc[4][4] = {};
    gemm_accum(A, W, nrows, wlds, acc, row0);
    gemm_epilogue(b, Cf, Cb, ldb, coloff, nrows, acc, row0);
}

// batched: y=0 -> kv table k-half (bf16), y=1 -> kv v-half (bf16), y=2 -> qt_e f32
__launch_bounds__(512)
__global__ void gemm_x3(const float* __restrict__ A,
        const float* __restrict__ W5, const float* __restrict__ b5,
        const float* __restrict__ W6, const float* __restrict__ b6,
        const float* __restrict__ W12, const float* __restrict__ b12,
        unsigned short* __restrict__ kv, float* __restrict__ qt, int nrows) {
    __shared__ __align__(16) float wlds[16384];
    const int rs = threadIdx.x >> 5;
    const int row0 = blockIdx.x * 64 + rs * 4;
    const int y = blockIdx.y;
    const float* W = y == 0 ? W5 : (y == 1 ? W6 : W12);
    const float* b = y == 0 ? b5 : (y == 1 ? b6 : b12);
    float acc[4][4] = {};
    gemm_accum(A, W, nrows, wlds, acc, row0);
    if (y == 2) gemm_epilogue(b, qt, nullptr, 0, 0, nrows, acc, row0);
    else        gemm_epilogue(b, nullptr, kv, 256, y == 0 ? 0 : 128, nrows, acc, row0);
}

// ---------------- tiny precompute kernels ----------------
__global__ void transpose128(const float* __restrict__ W, float* __restrict__ WT) {
    int i = blockIdx.x * 256 + threadIdx.x;   // 64 blocks
    if (i < 128 * 128) WT[(i & 127) * 128 + (i >> 7)] = W[i];
}

__global__ void prep_vecs(const float* __restrict__ W1, const float* __restrict__ W2,
                          const float* __restrict__ b1, const float* __restrict__ b2,
                          float* __restrict__ b12, float* __restrict__ w1b2,
                          float* __restrict__ s12) {
    int t = threadIdx.x;  // 256
    if (t < 128) {
        float acc = 0.f;
        for (int j = 0; j < 128; ++j) acc += W2[t * 128 + j] * b1[j];
        b12[t] = acc;
    } else {
        int k = t - 128;
        float acc = 0.f;
        for (int j = 0; j < 128; ++j) acc += W1[k * 128 + j] * b2[j];
        w1b2[k] = acc;
    }
    if (t == 0) {
        float acc = 0.f;
        for (int j = 0; j < 128; ++j) acc += b1[j] * b2[j];
        *s12 = acc;
    }
}

__global__ void prep_w3c(const float* __restrict__ W3, const float* __restrict__ Wc,
                         const float* __restrict__ b3, float* __restrict__ W3c,
                         float* __restrict__ b3c) {
    int i = blockIdx.x * 256 + threadIdx.x;
    if (i < 1280) {
        int k = i / 10, c = i % 10;
        float acc = 0.f;
        for (int j = 0; j < 128; ++j) acc += W3[k * 128 + j] * Wc[j * 10 + c];
        W3c[i] = acc;
    } else if (i < 1290) {
        int c = i - 1280;
        float acc = 0.f;
        for (int j = 0; j < 128; ++j) acc += b3[j] * Wc[j * 10 + c];
        b3c[c] = acc;
    }
}

// c_e[m] = feat_e[m].w1b2 + s12   (one wave per row)
__launch_bounds__(256)
__global__ void dotc(const float* __restrict__ X, const float* __restrict__ w1b2,
                     const float* __restrict__ s12, float* __restrict__ c_e, int M) {
    int w = (blockIdx.x * blockDim.x + threadIdx.x) >> 6;
    int lane = threadIdx.x & 63;
    if (w >= M) return;
    float2 r = ((const float2*)(X + (size_t)w * 128))[lane];
    float2 u = ((const float2*)w1b2)[lane];
    float d = r.x * u.x + r.y * u.y;
    #pragma unroll
    for (int o = 32; o; o >>= 1) d += __shfl_xor(d, o, 64);
    if (lane == 0) c_e[w] = d + *s12;
}

// ---------------- stage 1: hyperedge -> node (1 wave/segment) ----------------
// q (bf16 row) dot k-half of kv row; value = v-half; online softmax in regs;
// output feat_v as bf16 row.
__launch_bounds__(256)
__global__ void attn_s1(const unsigned int* __restrict__ qv,   // N x 64 words
                        const unsigned int* __restrict__ kv,   // M x 128 words (k|v)
                        const int* __restrict__ off, const int* __restrict__ adj,
                        unsigned int* __restrict__ fv,         // N x 64 words
                        int nseg, float scale) {
    int seg = (blockIdx.x * blockDim.x + threadIdx.x) >> 6;
    int lane = threadIdx.x & 63;
    if (seg >= nseg) return;
    int beg = off[seg], end = off[seg + 1];
    float2 q = bf2x2(qv[(size_t)seg * 64 + lane]);
    float m = -INFINITY, l = 0.f;
    float2 a = {0.f, 0.f};
    if (beg < end) {
        int s = adj[beg];
        unsigned int kw = kv[(size_t)s * 128 + lane];
        unsigned int vw = kv[(size_t)s * 128 + 64 + lane];
        for (int i = beg; i < end; ++i) {
            unsigned int kc = kw, vc = vw;
            if (i + 1 < end) {                     // wave-uniform prefetch
                int s2 = adj[i + 1];
                kw = kv[(size_t)s2 * 128 + lane];
                vw = kv[(size_t)s2 * 128 + 64 + lane];
            }
            float2 kf = bf2x2(kc);
            float d = kf.x * q.x + kf.y * q.y;
            #pragma unroll
            for (int o = 32; o; o >>= 1) d += __shfl_xor(d, o, 64);
            d = (d >= 0.f ? d : 0.01f * d) * scale;
            float2 vf = bf2x2(vc);
            if (d <= m) {
                float p = __expf(d - m);
                l += p; a.x += p * vf.x; a.y += p * vf.y;
            } else {
                float r = __expf(m - d);           // first iter: exp(-inf)=0
                l = l * r + 1.f;
                a.x = a.x * r + vf.x; a.y = a.y * r + vf.y;
                m = d;
            }
        }
    }
    float inv = (l > 0.f) ? 1.f / l : 0.f;
    fv[(size_t)seg * 64 + lane] = f2bf(a.x * inv) | (f2bf(a.y * inv) << 16);
}

// ---------------- stage 2: node -> hyperedge (4-wave block/segment) ----------
__launch_bounds__(256)
__global__ void attn_s2(const float* __restrict__ QT, const float* __restrict__ cvec,
                        const unsigned int* __restrict__ fv,   // N x 64 words
                        const int* __restrict__ off, const int* __restrict__ adj,
                        float* __restrict__ agg, float* __restrict__ flag, float scale) {
    __shared__ float sm[4], sl[4];
    __shared__ float2 sa[4][64];
    const int seg = blockIdx.x;
    const int wid = threadIdx.x >> 6, lane = threadIdx.x & 63;
    const int beg = off[seg], end = off[seg + 1];
    const float2 q = ((const float2*)(QT + (size_t)seg * 128))[lane];
    const float cadd = cvec[seg];
    float m = -INFINITY, l = 0.f;
    float2 a = {0.f, 0.f};
    int i = beg + wid;
    if (i < end) {
        int s = adj[i];
        unsigned int rw = fv[(size_t)s * 64 + lane];
        for (; i < end; i += 4) {
            unsigned int cw = rw;
            if (i + 4 < end) {                     // wave-uniform prefetch
                int s2 = adj[i + 4];
                rw = fv[(size_t)s2 * 64 + lane];
            }
            float2 cur = bf2x2(cw);
            float d = cur.x * q.x + cur.y * q.y;
            #pragma unroll
            for (int o = 32; o; o >>= 1) d += __shfl_xor(d, o, 64);
            d += cadd;
            d = (d >= 0.f ? d : 0.01f * d) * scale;
            if (d <= m) {
                float p = __expf(d - m);
                l += p; a.x += p * cur.x; a.y += p * cur.y;
            } else {
                float r = __expf(m - d);
                l = l * r + 1.f;
                a.x = a.x * r + cur.x; a.y = a.y * r + cur.y;
                m = d;
            }
        }
    }
    if (lane == 0) { sm[wid] = m; sl[wid] = l; }
    sa[wid][lane] = a;
    __syncthreads();
    if (wid == 0) {
        float M2 = fmaxf(fmaxf(sm[0], sm[1]), fmaxf(sm[2], sm[3]));
        float L = 0.f;
        float2 acc = {0.f, 0.f};
        #pragma unroll
        for (int w = 0; w < 4; ++w) {
            float f = (sl[w] > 0.f) ? __expf(sm[w] - M2) : 0.f;  // guard all-empty NaN
            L += f * sl[w];
            float2 v = sa[w][lane];
            acc.x += f * v.x; acc.y += f * v.y;
        }
        float inv = (L > 0.f) ? 1.f / L : 0.f;
        ((float2*)(agg + (size_t)seg * 128))[lane] = make_float2(acc.x * inv, acc.y * inv);
        if (lane == 0) flag[seg] = (L > 0.f) ? 1.f : 0.f;
    }
}

// pred[m,c] = agg[m].W3c[:,c] + flag[m]*b3c[c] + bc[c]
__global__ void head2(const float* __restrict__ agg, const float* __restrict__ flag,
                      const float* __restrict__ W3c, const float* __restrict__ b3c,
                      const float* __restrict__ bc, float* __restrict__ out, int M) {
    int t = blockIdx.x * blockDim.x + threadIdx.x;
    if (t >= M * 10) return;
    int row = t / 10, c = t % 10;
    float acc = bc[c] + flag[row] * b3c[c];
    #pragma unroll 8
    for (int k = 0; k < 128; ++k)
        acc = fmaf(agg[(size_t)row * 128 + k], W3c[k * 10 + c], acc);
    out[t] = acc;
}

extern "C" void kernel_launch(void* const* d_in, const int* in_sizes, int n_in,
                              void* d_out, int out_size, void* d_ws, size_t ws_size,
                              hipStream_t stream) {
    const float* vfeat = (const float*)d_in[0];
    const float* efeat = (const float*)d_in[1];
    const int*   he    = (const int*)d_in[2];
    const int*   nd    = (const int*)d_in[3];
    const float* Wfl = (const float*)d_in[6],  *bfl = (const float*)d_in[7];
    const float* W1  = (const float*)d_in[8],  *b1  = (const float*)d_in[9];
    const float* W2  = (const float*)d_in[10], *b2  = (const float*)d_in[11];
    const float* W3  = (const float*)d_in[12], *b3  = (const float*)d_in[13];
    const float* W4  = (const float*)d_in[14], *b4  = (const float*)d_in[15];
    const float* W5  = (const float*)d_in[16], *b5  = (const float*)d_in[17];
    const float* W6  = (const float*)d_in[18], *b6  = (const float*)d_in[19];
    const float* Wc  = (const float*)d_in[20], *bc  = (const float*)d_in[21];
    float* out = (float*)d_out;
    float* ws  = (float*)d_ws;

    const int M = HY_M, N = HY_N, E = HY_E;

    // -------- workspace layout (float units) --------
    float* feat_e = ws + 0;          // 1.28M
    float* qt_e   = ws + 1280000;    // 1.28M
    float* agg    = ws + 2560000;    // 1.28M
    float* c_e    = ws + 3840000;    // 10K
    float* flag   = ws + 3850000;    // 10K
    float* W2T    = ws + 3860000;    // 16384
    float* W12    = ws + 3876384;    // 16384
    float* W3c    = ws + 3892768;    // 1280
    float* b3c    = ws + 3894048;    // 16
    float* b12    = ws + 3894064;    // 128
    float* w1b2   = ws + 3894192;    // 128
    float* s12    = ws + 3894320;    // 4
    float* zeros  = ws + 3894324;    // 128 (+pad)
    unsigned int* qv_bf = (unsigned int*)(ws + 3894512);   // N*64 words = 6.4M
    unsigned int* kv_bf = qv_bf + (size_t)N * 64;          // M*128 words = 1.28M
    unsigned int* fv_bf = kv_bf + (size_t)M * 128;         // N*64 words = 6.4M
    int* nd_off = (int*)(fv_bf + (size_t)N * 64);          // 100001
    int* he_off = nd_off + 100001;                          // 10001
    int* nd_adj = he_off + 10001;                           // 640000 (stores he[e])
    int* he_adj = nd_adj + 640000;                          // 640000 (stores nd[e])
    // CSR-build scratch overlays fv_bf (dead until attn_s1 writes it)
    int* ncnt = (int*)fv_bf;                                // N
    int* ncur = ncnt + N;                                   // N
    int* hcnt = ncur + N;                                   // M
    int* hcur = hcnt + M;                                   // M
    int* bsN  = hcur + M;                                   // 128
    int* bsM  = bsN + 128;                                  // 128

    const float scale = 0.08838834764831843f;  // 1/sqrt(128)

    // -------- CSR builds (both orientations) --------
    zero_ints<<<(2 * N + 2 * M + 255) / 256, 256, 0, stream>>>(ncnt, 2 * N + 2 * M);
    hist2<<<(E + 255) / 256, 256, 0, stream>>>(nd, he, ncnt, hcnt, E);
    {
        int nbN = (N + 1023) / 1024, nbM = (M + 1023) / 1024;
        scanA<<<nbN, 256, 0, stream>>>(ncnt, bsN, N);
        scanB<<<1, 256, 0, stream>>>(bsN, nbN);
        scanC<<<nbN, 256, 0, stream>>>(ncnt, bsN, nd_off, N, E);
        scanA<<<nbM, 256, 0, stream>>>(hcnt, bsM, M);
        scanB<<<1, 256, 0, stream>>>(bsM, nbM);
        scanC<<<nbM, 256, 0, stream>>>(hcnt, bsM, he_off, M, E);
    }
    fill2<<<(E + 255) / 256, 256, 0, stream>>>(nd, he, nd_off, he_off,
                                               ncur, hcur, nd_adj, he_adj, E);

    // -------- weight precomputes --------
    transpose128<<<64, 256, 0, stream>>>(W2, W2T);
    fillk<<<1, 128, 0, stream>>>(zeros, 0.f, 128);
    prep_vecs<<<1, 256, 0, stream>>>(W1, W2, b1, b2, b12, w1b2, s12);
    gemm_uni<<<2, 512, 0, stream>>>(W1, W2T, zeros, W12, nullptr, 0, 0, 128);
    prep_w3c<<<6, 256, 0, stream>>>(W3, Wc, b3, W3c, b3c);

    // -------- dense layers --------
    gemm_uni<<<(M + 63) / 64, 512, 0, stream>>>(efeat, Wfl, bfl, feat_e,
                                                nullptr, 0, 0, M);
    gemm_x3<<<dim3((M + 63) / 64, 3), 512, 0, stream>>>(
        feat_e, W5, b5, W6, b6, W12, b12, (unsigned short*)kv_bf, qt_e, M);
    dotc<<<(M * 64 + 255) / 256, 256, 0, stream>>>(feat_e, w1b2, s12, c_e, M);
    gemm_uni<<<(N + 63) / 64, 512, 0, stream>>>(vfeat, W4, b4, nullptr,
                                                (unsigned short*)qv_bf, 128, 0, N);

    // -------- stage 1: hyperedge -> node --------
    attn_s1<<<(N * 64 + 255) / 256, 256, 0, stream>>>(
        qv_bf, kv_bf, nd_off, nd_adj, fv_bf, N, scale);

    // -------- stage 2: node -> hyperedge --------
    attn_s2<<<M, 256, 0, stream>>>(qt_e, c_e, fv_bf, he_off, he_adj, agg, flag, scale);

    // -------- head --------
    head2<<<(M * 10 + 255) / 256, 256, 0, stream>>>(agg, flag, W3c, b3c, bc, out, M);
}

// Round 6
// 391.470 us; speedup vs baseline: 3.1554x; 1.1520x over previous
//
#include <hip/hip_runtime.h>
#include <hip/hip_bf16.h>
#include <math.h>

// ---------------------------------------------------------------------------
// Seq_HyGAN round 6: 16-lane-group attention.
//  Rows are 256B bf16 -> 16 lanes x 16B covers a row. Each 16-lane group owns
//  one edge: 4-step shuffle reduce (was 6-step over 64 lanes), online softmax
//  branchless. attn_s1: 4 segments/wave. attn_s2: 16 groups per 4-wave block
//  strided over the segment edge list, LDS merge at the end.
// ---------------------------------------------------------------------------

#define HY_M 10000
#define HY_N 100000
#define HY_E 640000

// ---- bf16 helpers (manual, RN) ----
__device__ __forceinline__ unsigned int f2bf(float x) {
    unsigned int u = __float_as_uint(x);
    return (u + 0x7fffu + ((u >> 16) & 1u)) >> 16;
}
__device__ __forceinline__ float2 bf2x2(unsigned int w) {   // elems (2l, 2l+1)
    float lo = __uint_as_float(w << 16);
    float hi = __uint_as_float(w & 0xffff0000u);
    return make_float2(lo, hi);
}

// ---------------- small utility kernels ----------------
__global__ void zero_ints(int* __restrict__ p, int n) {
    int i = blockIdx.x * blockDim.x + threadIdx.x;
    if (i < n) p[i] = 0;
}

__global__ void fillk(float* __restrict__ p, float v, int n) {
    int stride = gridDim.x * blockDim.x;
    for (int i = blockIdx.x * blockDim.x + threadIdx.x; i < n; i += stride) p[i] = v;
}

__global__ void hist2(const int* __restrict__ nd, const int* __restrict__ he,
                      int* __restrict__ ncnt, int* __restrict__ hcnt, int E) {
    int e = blockIdx.x * blockDim.x + threadIdx.x;
    if (e < E) { atomicAdd(&ncnt[nd[e]], 1); atomicAdd(&hcnt[he[e]], 1); }
}

__global__ void scanA(const int* __restrict__ cnt, int* __restrict__ bsum, int n) {
    __shared__ int s[256];
    int t = threadIdx.x, base = blockIdx.x * 1024;
    int v = 0;
    for (int i = t; i < 1024; i += 256) { int g = base + i; if (g < n) v += cnt[g]; }
    s[t] = v; __syncthreads();
    for (int off = 128; off; off >>= 1) { if (t < off) s[t] += s[t + off]; __syncthreads(); }
    if (t == 0) bsum[blockIdx.x] = s[0];
}

__global__ void scanB(int* __restrict__ bsum, int nb) {   // single block, nb<=256
    __shared__ int s[256];
    int t = threadIdx.x;
    int orig = (t < nb) ? bsum[t] : 0;
    s[t] = orig; __syncthreads();
    for (int off = 1; off < 256; off <<= 1) {
        int v = (t >= off) ? s[t - off] : 0;
        __syncthreads(); s[t] += v; __syncthreads();
    }
    if (t < nb) bsum[t] = s[t] - orig;  // exclusive
}

__global__ void scanC(const int* __restrict__ cnt, const int* __restrict__ bsum,
                      int* __restrict__ off, int n, int total) {
    __shared__ int s[256];
    int t = threadIdx.x, base = blockIdx.x * 1024;
    int idx = base + t * 4;
    int v[4], sum = 0;
    #pragma unroll
    for (int j = 0; j < 4; ++j) { v[j] = (idx + j < n) ? cnt[idx + j] : 0; sum += v[j]; }
    int orig = sum;
    s[t] = sum; __syncthreads();
    for (int o = 1; o < 256; o <<= 1) {
        int x = (t >= o) ? s[t - o] : 0;
        __syncthreads(); s[t] += x; __syncthreads();
    }
    int excl = s[t] - orig + bsum[blockIdx.x];
    #pragma unroll
    for (int j = 0; j < 4; ++j) { if (idx + j < n) off[idx + j] = excl; excl += v[j]; }
    if (blockIdx.x == 0 && t == 0) off[n] = total;
}

__global__ void fill2(const int* __restrict__ nd, const int* __restrict__ he,
                      const int* __restrict__ noff, const int* __restrict__ hoff,
                      int* __restrict__ ncur, int* __restrict__ hcur,
                      int* __restrict__ nadj, int* __restrict__ hadj, int E) {
    int e = blockIdx.x * blockDim.x + threadIdx.x;
    if (e >= E) return;
    int d = nd[e], h = he[e];
    nadj[noff[d] + atomicAdd(&ncur[d], 1)] = h;
    hadj[hoff[h] + atomicAdd(&hcur[h], 1)] = d;
}

// ---------------- dense f32 GEMM core: K=N=128, 64-row tiles, W-only LDS -----
__device__ __forceinline__ void gemm_accum(const float* __restrict__ A,
        const float* __restrict__ W, int nrows, float* wlds,
        float (&acc)[4][4], int row0) {
    const int tid = threadIdx.x;
    const int cg = tid & 31;
    for (int i = tid; i < 4096; i += 512)
        ((float4*)wlds)[i] = ((const float4*)W)[i];
    __syncthreads();
    const float4* A0 = (const float4*)(A + (size_t)min(row0 + 0, nrows - 1) * 128);
    const float4* A1 = (const float4*)(A + (size_t)min(row0 + 1, nrows - 1) * 128);
    const float4* A2 = (const float4*)(A + (size_t)min(row0 + 2, nrows - 1) * 128);
    const float4* A3 = (const float4*)(A + (size_t)min(row0 + 3, nrows - 1) * 128);
    #pragma unroll 2
    for (int kq = 0; kq < 32; ++kq) {
        float4 ar[4] = {A0[kq], A1[kq], A2[kq], A3[kq]};    // wave-broadcast loads
        const float4* wk = (const float4*)(wlds + kq * 512);
        float4 wr[4] = {wk[cg], wk[32 + cg], wk[64 + cg], wk[96 + cg]};
        #pragma unroll
        for (int r = 0; r < 4; ++r) {
            float av[4] = {ar[r].x, ar[r].y, ar[r].z, ar[r].w};
            #pragma unroll
            for (int j = 0; j < 4; ++j) {
                float wv[4] = {wr[j].x, wr[j].y, wr[j].z, wr[j].w};
                #pragma unroll
                for (int c = 0; c < 4; ++c)
                    acc[r][c] = fmaf(av[j], wv[c], acc[r][c]);
            }
        }
    }
}

// epilogue: optional f32 store (Cf, row stride 128) and/or bf16 store
// (Cb ushort base, row stride ldb ushorts, column offset coloff).
__device__ __forceinline__ void gemm_epilogue(const float* __restrict__ b,
        float* __restrict__ Cf, unsigned short* __restrict__ Cb, int ldb, int coloff,
        int nrows, float (&acc)[4][4], int row0) {
    const int cg = threadIdx.x & 31;
    const float4 bv = ((const float4*)b)[cg];
    #pragma unroll
    for (int r = 0; r < 4; ++r) {
        int gr = row0 + r;
        if (gr < nrows) {
            float o0 = acc[r][0] + bv.x, o1 = acc[r][1] + bv.y;
            float o2 = acc[r][2] + bv.z, o3 = acc[r][3] + bv.w;
            if (Cf) {
                float4 o = {o0, o1, o2, o3};
                ((float4*)(Cf + (size_t)gr * 128))[cg] = o;
            }
            if (Cb) {
                uint2 pk;
                pk.x = f2bf(o0) | (f2bf(o1) << 16);
                pk.y = f2bf(o2) | (f2bf(o3) << 16);
                *(uint2*)(Cb + (size_t)gr * ldb + coloff + cg * 4) = pk;
            }
        }
    }
}

__launch_bounds__(512)
__global__ void gemm_uni(const float* __restrict__ A, const float* __restrict__ W,
                         const float* __restrict__ b, float* __restrict__ Cf,
                         unsigned short* __restrict__ Cb, int ldb, int coloff, int nrows) {
    __shared__ __align__(16) float wlds[16384];
    const int rs = threadIdx.x >> 5;
    const int row0 = blockIdx.x * 64 + rs * 4;
    float acc[4][4] = {};
    gemm_accum(A, W, nrows, wlds, acc, row0);
    gemm_epilogue(b, Cf, Cb, ldb, coloff, nrows, acc, row0);
}

// batched: y=0 -> kv table k-half (bf16), y=1 -> kv v-half (bf16), y=2 -> qt_e f32
__launch_bounds__(512)
__global__ void gemm_x3(const float* __restrict__ A,
        const float* __restrict__ W5, const float* __restrict__ b5,
        const float* __restrict__ W6, const float* __restrict__ b6,
        const float* __restrict__ W12, const float* __restrict__ b12,
        unsigned short* __restrict__ kv, float* __restrict__ qt, int nrows) {
    __shared__ __align__(16) float wlds[16384];
    const int rs = threadIdx.x >> 5;
    const int row0 = blockIdx.x * 64 + rs * 4;
    const int y = blockIdx.y;
    const float* W = y == 0 ? W5 : (y == 1 ? W6 : W12);
    const float* b = y == 0 ? b5 : (y == 1 ? b6 : b12);
    float acc[4][4] = {};
    gemm_accum(A, W, nrows, wlds, acc, row0);
    if (y == 2) gemm_epilogue(b, qt, nullptr, 0, 0, nrows, acc, row0);
    else        gemm_epilogue(b, nullptr, kv, 256, y == 0 ? 0 : 128, nrows, acc, row0);
}

// ---------------- tiny precompute kernels ----------------
__global__ void transpose128(const float* __restrict__ W, float* __restrict__ WT) {
    int i = blockIdx.x * 256 + threadIdx.x;   // 64 blocks
    if (i < 128 * 128) WT[(i & 127) * 128 + (i >> 7)] = W[i];
}

__global__ void prep_vecs(const float* __restrict__ W1, const float* __restrict__ W2,
                          const float* __restrict__ b1, const float* __restrict__ b2,
                          float* __restrict__ b12, float* __restrict__ w1b2,
                          float* __restrict__ s12) {
    int t = threadIdx.x;  // 256
    if (t < 128) {
        float acc = 0.f;
        for (int j = 0; j < 128; ++j) acc += W2[t * 128 + j] * b1[j];
        b12[t] = acc;
    } else {
        int k = t - 128;
        float acc = 0.f;
        for (int j = 0; j < 128; ++j) acc += W1[k * 128 + j] * b2[j];
        w1b2[k] = acc;
    }
    if (t == 0) {
        float acc = 0.f;
        for (int j = 0; j < 128; ++j) acc += b1[j] * b2[j];
        *s12 = acc;
    }
}

__global__ void prep_w3c(const float* __restrict__ W3, const float* __restrict__ Wc,
                         const float* __restrict__ b3, float* __restrict__ W3c,
                         float* __restrict__ b3c) {
    int i = blockIdx.x * 256 + threadIdx.x;
    if (i < 1280) {
        int k = i / 10, c = i % 10;
        float acc = 0.f;
        for (int j = 0; j < 128; ++j) acc += W3[k * 128 + j] * Wc[j * 10 + c];
        W3c[i] = acc;
    } else if (i < 1290) {
        int c = i - 1280;
        float acc = 0.f;
        for (int j = 0; j < 128; ++j) acc += b3[j] * Wc[j * 10 + c];
        b3c[c] = acc;
    }
}

// c_e[m] = feat_e[m].w1b2 + s12   (one wave per row)
__launch_bounds__(256)
__global__ void dotc(const float* __restrict__ X, const float* __restrict__ w1b2,
                     const float* __restrict__ s12, float* __restrict__ c_e, int M) {
    int w = (blockIdx.x * blockDim.x + threadIdx.x) >> 6;
    int lane = threadIdx.x & 63;
    if (w >= M) return;
    float2 r = ((const float2*)(X + (size_t)w * 128))[lane];
    float2 u = ((const float2*)w1b2)[lane];
    float d = r.x * u.x + r.y * u.y;
    #pragma unroll
    for (int o = 32; o; o >>= 1) d += __shfl_xor(d, o, 64);
    if (lane == 0) c_e[w] = d + *s12;
}

// ---------------- stage 1: hyperedge -> node --------------------------------
// 16-lane group per segment (4 segments/wave). lane j owns dims 8j..8j+7.
__launch_bounds__(256)
__global__ void attn_s1(const unsigned int* __restrict__ qv,   // N x 64 words
                        const unsigned int* __restrict__ kv,   // M x 128 words (k|v)
                        const int* __restrict__ off, const int* __restrict__ adj,
                        unsigned int* __restrict__ fv,         // N x 64 words
                        int nseg, float scale) {
    int seg = (blockIdx.x * blockDim.x + threadIdx.x) >> 4;
    int j = threadIdx.x & 15;
    if (seg >= nseg) return;
    int beg = off[seg], end = off[seg + 1];
    uint4 qw = ((const uint4*)(qv + (size_t)seg * 64))[j];
    float2 q0 = bf2x2(qw.x), q1 = bf2x2(qw.y), q2 = bf2x2(qw.z), q3 = bf2x2(qw.w);
    float m = -INFINITY, l = 0.f;
    float a[8] = {};
    if (beg < end) {
        int s = adj[beg];
        uint4 kw = ((const uint4*)(kv + (size_t)s * 128))[j];
        uint4 vw = ((const uint4*)(kv + (size_t)s * 128 + 64))[j];
        for (int i = beg; i < end; ++i) {
            uint4 kc = kw, vc = vw;
            if (i + 1 < end) {                     // group-uniform prefetch
                int s2 = adj[i + 1];
                kw = ((const uint4*)(kv + (size_t)s2 * 128))[j];
                vw = ((const uint4*)(kv + (size_t)s2 * 128 + 64))[j];
            }
            float2 k0 = bf2x2(kc.x), k1 = bf2x2(kc.y), k2 = bf2x2(kc.z), k3 = bf2x2(kc.w);
            float d = k0.x * q0.x + k0.y * q0.y + k1.x * q1.x + k1.y * q1.y
                    + k2.x * q2.x + k2.y * q2.y + k3.x * q3.x + k3.y * q3.y;
            d += __shfl_xor(d, 8); d += __shfl_xor(d, 4);
            d += __shfl_xor(d, 2); d += __shfl_xor(d, 1);
            d = (d >= 0.f ? d : 0.01f * d) * scale;
            float2 v0 = bf2x2(vc.x), v1 = bf2x2(vc.y), v2 = bf2x2(vc.z), v3 = bf2x2(vc.w);
            float vf[8] = {v0.x, v0.y, v1.x, v1.y, v2.x, v2.y, v3.x, v3.y};
            float mn = fmaxf(m, d);
            float r = __expf(m - mn);              // first iter: exp(-inf)=0
            float p = __expf(d - mn);
            l = l * r + p;
            #pragma unroll
            for (int t = 0; t < 8; ++t) a[t] = a[t] * r + p * vf[t];
            m = mn;
        }
    }
    float inv = (l > 0.f) ? 1.f / l : 0.f;
    uint4 o;
    o.x = f2bf(a[0] * inv) | (f2bf(a[1] * inv) << 16);
    o.y = f2bf(a[2] * inv) | (f2bf(a[3] * inv) << 16);
    o.z = f2bf(a[4] * inv) | (f2bf(a[5] * inv) << 16);
    o.w = f2bf(a[6] * inv) | (f2bf(a[7] * inv) << 16);
    ((uint4*)(fv + (size_t)seg * 64))[j] = o;
}

// ---------------- stage 2: node -> hyperedge --------------------------------
// one 256-thread block per segment = 16 groups strided over the edge list.
__launch_bounds__(256)
__global__ void attn_s2(const float* __restrict__ QT, const float* __restrict__ cvec,
                        const unsigned int* __restrict__ fv,   // N x 64 words
                        const int* __restrict__ off, const int* __restrict__ adj,
                        float* __restrict__ agg, float* __restrict__ flag, float scale) {
    __shared__ float sm[16], sl[16];
    __shared__ float sacc[16][16][9];              // pad 9: conflict-free scalar access
    const int seg = blockIdx.x;
    const int g = threadIdx.x >> 4;                // group 0..15
    const int j = threadIdx.x & 15;                // dims 8j..8j+7
    const int beg = off[seg], end = off[seg + 1];
    const float4 qa = ((const float4*)(QT + (size_t)seg * 128 + 8 * j))[0];
    const float4 qb = ((const float4*)(QT + (size_t)seg * 128 + 8 * j))[1];
    const float cadd = cvec[seg];
    float m = -INFINITY, l = 0.f;
    float a[8] = {};
    int i = beg + g;
    if (i < end) {
        int s = adj[i];
        uint4 rw = ((const uint4*)(fv + (size_t)s * 64))[j];
        for (; i < end; i += 16) {
            uint4 rc = rw;
            if (i + 16 < end) {                    // group-uniform prefetch
                int s2 = adj[i + 16];
                rw = ((const uint4*)(fv + (size_t)s2 * 64))[j];
            }
            float2 r0 = bf2x2(rc.x), r1 = bf2x2(rc.y), r2 = bf2x2(rc.z), r3 = bf2x2(rc.w);
            float rf[8] = {r0.x, r0.y, r1.x, r1.y, r2.x, r2.y, r3.x, r3.y};
            float d = rf[0] * qa.x + rf[1] * qa.y + rf[2] * qa.z + rf[3] * qa.w
                    + rf[4] * qb.x + rf[5] * qb.y + rf[6] * qb.z + rf[7] * qb.w;
            d += __shfl_xor(d, 8); d += __shfl_xor(d, 4);
            d += __shfl_xor(d, 2); d += __shfl_xor(d, 1);
            d += cadd;
            d = (d >= 0.f ? d : 0.01f * d) * scale;
            float mn = fmaxf(m, d);
            float r = __expf(m - mn);
            float p = __expf(d - mn);
            l = l * r + p;
            #pragma unroll
            for (int t = 0; t < 8; ++t) a[t] = a[t] * r + p * rf[t];
            m = mn;
        }
    }
    if (j == 0) { sm[g] = m; sl[g] = l; }          // m,l group-uniform
    #pragma unroll
    for (int t = 0; t < 8; ++t) sacc[g][j][t] = a[t];
    __syncthreads();
    if (threadIdx.x < 16) {                        // lane = j, merge 16 states
        float M2 = -INFINITY;
        #pragma unroll 4
        for (int gg = 0; gg < 16; ++gg) if (sl[gg] > 0.f) M2 = fmaxf(M2, sm[gg]);
        float L = 0.f;
        float acc[8] = {};
        #pragma unroll 4
        for (int gg = 0; gg < 16; ++gg) {
            float f = (sl[gg] > 0.f) ? __expf(sm[gg] - M2) : 0.f;
            L += f * sl[gg];
            #pragma unroll
            for (int t = 0; t < 8; ++t) acc[t] += f * sacc[gg][threadIdx.x][t];
        }
        float inv = (L > 0.f) ? 1.f / L : 0.f;
        float4 o1 = {acc[0] * inv, acc[1] * inv, acc[2] * inv, acc[3] * inv};
        float4 o2 = {acc[4] * inv, acc[5] * inv, acc[6] * inv, acc[7] * inv};
        ((float4*)(agg + (size_t)seg * 128 + 8 * threadIdx.x))[0] = o1;
        ((float4*)(agg + (size_t)seg * 128 + 8 * threadIdx.x))[1] = o2;
        if (threadIdx.x == 0) flag[seg] = (L > 0.f) ? 1.f : 0.f;
    }
}

// pred[m,c] = agg[m].W3c[:,c] + flag[m]*b3c[c] + bc[c]
__global__ void head2(const float* __restrict__ agg, const float* __restrict__ flag,
                      const float* __restrict__ W3c, const float* __restrict__ b3c,
                      const float* __restrict__ bc, float* __restrict__ out, int M) {
    int t = blockIdx.x * blockDim.x + threadIdx.x;
    if (t >= M * 10) return;
    int row = t / 10, c = t % 10;
    float acc = bc[c] + flag[row] * b3c[c];
    #pragma unroll 8
    for (int k = 0; k < 128; ++k)
        acc = fmaf(agg[(size_t)row * 128 + k], W3c[k * 10 + c], acc);
    out[t] = acc;
}

extern "C" void kernel_launch(void* const* d_in, const int* in_sizes, int n_in,
                              void* d_out, int out_size, void* d_ws, size_t ws_size,
                              hipStream_t stream) {
    const float* vfeat = (const float*)d_in[0];
    const float* efeat = (const float*)d_in[1];
    const int*   he    = (const int*)d_in[2];
    const int*   nd    = (const int*)d_in[3];
    const float* Wfl = (const float*)d_in[6],  *bfl = (const float*)d_in[7];
    const float* W1  = (const float*)d_in[8],  *b1  = (const float*)d_in[9];
    const float* W2  = (const float*)d_in[10], *b2  = (const float*)d_in[11];
    const float* W3  = (const float*)d_in[12], *b3  = (const float*)d_in[13];
    const float* W4  = (const float*)d_in[14], *b4  = (const float*)d_in[15];
    const float* W5  = (const float*)d_in[16], *b5  = (const float*)d_in[17];
    const float* W6  = (const float*)d_in[18], *b6  = (const float*)d_in[19];
    const float* Wc  = (const float*)d_in[20], *bc  = (const float*)d_in[21];
    float* out = (float*)d_out;
    float* ws  = (float*)d_ws;

    const int M = HY_M, N = HY_N, E = HY_E;

    // -------- workspace layout (float units) --------
    float* feat_e = ws + 0;          // 1.28M
    float* qt_e   = ws + 1280000;    // 1.28M
    float* agg    = ws + 2560000;    // 1.28M
    float* c_e    = ws + 3840000;    // 10K
    float* flag   = ws + 3850000;    // 10K
    float* W2T    = ws + 3860000;    // 16384
    float* W12    = ws + 3876384;    // 16384
    float* W3c    = ws + 3892768;    // 1280
    float* b3c    = ws + 3894048;    // 16
    float* b12    = ws + 3894064;    // 128
    float* w1b2   = ws + 3894192;    // 128
    float* s12    = ws + 3894320;    // 4
    float* zeros  = ws + 3894324;    // 128 (+pad)
    unsigned int* qv_bf = (unsigned int*)(ws + 3894512);   // N*64 words = 6.4M
    unsigned int* kv_bf = qv_bf + (size_t)N * 64;          // M*128 words = 1.28M
    unsigned int* fv_bf = kv_bf + (size_t)M * 128;         // N*64 words = 6.4M
    int* nd_off = (int*)(fv_bf + (size_t)N * 64);          // 100001
    int* he_off = nd_off + 100001;                          // 10001
    int* nd_adj = he_off + 10001;                           // 640000 (stores he[e])
    int* he_adj = nd_adj + 640000;                          // 640000 (stores nd[e])
    // CSR-build scratch overlays fv_bf (dead until attn_s1 writes it)
    int* ncnt = (int*)fv_bf;                                // N
    int* ncur = ncnt + N;                                   // N
    int* hcnt = ncur + N;                                   // M
    int* hcur = hcnt + M;                                   // M
    int* bsN  = hcur + M;                                   // 128
    int* bsM  = bsN + 128;                                  // 128

    const float scale = 0.08838834764831843f;  // 1/sqrt(128)

    // -------- CSR builds (both orientations) --------
    zero_ints<<<(2 * N + 2 * M + 255) / 256, 256, 0, stream>>>(ncnt, 2 * N + 2 * M);
    hist2<<<(E + 255) / 256, 256, 0, stream>>>(nd, he, ncnt, hcnt, E);
    {
        int nbN = (N + 1023) / 1024, nbM = (M + 1023) / 1024;
        scanA<<<nbN, 256, 0, stream>>>(ncnt, bsN, N);
        scanB<<<1, 256, 0, stream>>>(bsN, nbN);
        scanC<<<nbN, 256, 0, stream>>>(ncnt, bsN, nd_off, N, E);
        scanA<<<nbM, 256, 0, stream>>>(hcnt, bsM, M);
        scanB<<<1, 256, 0, stream>>>(bsM, nbM);
        scanC<<<nbM, 256, 0, stream>>>(hcnt, bsM, he_off, M, E);
    }
    fill2<<<(E + 255) / 256, 256, 0, stream>>>(nd, he, nd_off, he_off,
                                               ncur, hcur, nd_adj, he_adj, E);

    // -------- weight precomputes --------
    transpose128<<<64, 256, 0, stream>>>(W2, W2T);
    fillk<<<1, 128, 0, stream>>>(zeros, 0.f, 128);
    prep_vecs<<<1, 256, 0, stream>>>(W1, W2, b1, b2, b12, w1b2, s12);
    gemm_uni<<<2, 512, 0, stream>>>(W1, W2T, zeros, W12, nullptr, 0, 0, 128);
    prep_w3c<<<6, 256, 0, stream>>>(W3, Wc, b3, W3c, b3c);

    // -------- dense layers --------
    gemm_uni<<<(M + 63) / 64, 512, 0, stream>>>(efeat, Wfl, bfl, feat_e,
                                                nullptr, 0, 0, M);
    gemm_x3<<<dim3((M + 63) / 64, 3), 512, 0, stream>>>(
        feat_e, W5, b5, W6, b6, W12, b12, (unsigned short*)kv_bf, qt_e, M);
    dotc<<<(M * 64 + 255) / 256, 256, 0, stream>>>(feat_e, w1b2, s12, c_e, M);
    gemm_uni<<<(N + 63) / 64, 512, 0, stream>>>(vfeat, W4, b4, nullptr,
                                                (unsigned short*)qv_bf, 128, 0, N);

    // -------- stage 1: hyperedge -> node (16-lane groups, 4 seg/wave) --------
    attn_s1<<<(N * 16 + 255) / 256, 256, 0, stream>>>(
        qv_bf, kv_bf, nd_off, nd_adj, fv_bf, N, scale);

    // -------- stage 2: node -> hyperedge (16 groups per block) --------
    attn_s2<<<M, 256, 0, stream>>>(qt_e, c_e, fv_bf, he_off, he_adj, agg, flag, scale);

    // -------- head --------
    head2<<<(M * 10 + 255) / 256, 256, 0, stream>>>(agg, flag, W3c, b3c, bc, out, M);
}

// Round 7
// 273.582 us; speedup vs baseline: 4.5151x; 1.4309x over previous
//
#include <hip/hip_runtime.h>
#include <hip/hip_bf16.h>
#include <math.h>

// ---------------------------------------------------------------------------
// Seq_HyGAN round 7: bucketed counting-sort CSR build.
//  fill2's 16x write amplification (85 MB, 92us) replaced by:
//   pass0 coarse hist (LDS) -> coarse scan -> pass1 bucket partition
//   (per-block reservation, near-coalesced staging writes) -> pass2 per-bucket
//   fine hist + LDS scan (produces fine CSR offsets, replacing hist2+6 scans)
//   + block-local scatter (single-XCD L2 region -> full line merge).
//  Attention/GEMM pipeline unchanged from round 6.
// ---------------------------------------------------------------------------

#define HY_M 10000
#define HY_N 100000
#define HY_E 640000

#define SH_N 9              // node bucket width 512
#define NB_N 196            // ceil(100000/512)
#define SH_M 6              // hedge bucket width 64
#define NB_M 157            // ceil(10000/64)

// ---- bf16 helpers (manual, RN) ----
__device__ __forceinline__ unsigned int f2bf(float x) {
    unsigned int u = __float_as_uint(x);
    return (u + 0x7fffu + ((u >> 16) & 1u)) >> 16;
}
__device__ __forceinline__ float2 bf2x2(unsigned int w) {   // elems (2l, 2l+1)
    float lo = __uint_as_float(w << 16);
    float hi = __uint_as_float(w & 0xffff0000u);
    return make_float2(lo, hi);
}

// ---------------- small utility kernels ----------------
__global__ void zero_ints(int* __restrict__ p, int n) {
    int i = blockIdx.x * blockDim.x + threadIdx.x;
    if (i < n) p[i] = 0;
}

__global__ void fillk(float* __restrict__ p, float v, int n) {
    int stride = gridDim.x * blockDim.x;
    for (int i = blockIdx.x * blockDim.x + threadIdx.x; i < n; i += stride) p[i] = v;
}

// ---------------- CSR build: bucketed counting sort ----------------
// pass0: coarse bucket histograms for both orientations.
__launch_bounds__(256)
__global__ void coarse_hist(const int* __restrict__ nd, const int* __restrict__ he,
                            int* __restrict__ gcntN, int* __restrict__ gcntM, int E) {
    __shared__ int hN[256], hM[256];
    const int t = threadIdx.x;
    hN[t] = 0; hM[t] = 0;
    __syncthreads();
    const int base = blockIdx.x * 4096;
    for (int i = t; i < 4096; i += 256) {
        int e = base + i;
        if (e < E) {
            atomicAdd(&hN[nd[e] >> SH_N], 1);
            atomicAdd(&hM[he[e] >> SH_M], 1);
        }
    }
    __syncthreads();
    if (hN[t]) atomicAdd(&gcntN[t], hN[t]);
    if (hM[t]) atomicAdd(&gcntM[t], hM[t]);
}

// coarse exclusive scan (block 0 -> N table, block 1 -> M table)
__global__ void coarse_scan(const int* __restrict__ gcntN, const int* __restrict__ gcntM,
                            int* __restrict__ coffN, int* __restrict__ coffM, int E) {
    __shared__ int s[256];
    const int* g = blockIdx.x ? gcntM : gcntN;
    int* o = blockIdx.x ? coffM : coffN;
    const int nb = blockIdx.x ? NB_M : NB_N;
    const int t = threadIdx.x;
    int v = (t < nb) ? g[t] : 0;
    int orig = v;
    s[t] = v; __syncthreads();
    for (int off = 1; off < 256; off <<= 1) {
        int x = (t >= off) ? s[t - off] : 0;
        __syncthreads(); s[t] += x; __syncthreads();
    }
    if (t < nb) o[t] = s[t] - orig;
    if (t == 0) o[nb] = E;
}

// pass1: partition edges into bucket-grouped staging (packed local_dst|src).
__launch_bounds__(256)
__global__ void part_scatter(const int* __restrict__ nd, const int* __restrict__ he,
                             const int* __restrict__ coffN, const int* __restrict__ coffM,
                             int* __restrict__ gcurN, int* __restrict__ gcurM,
                             unsigned int* __restrict__ stN, unsigned int* __restrict__ stM,
                             int E) {
    __shared__ int hN[256], hM[256];
    const int t = threadIdx.x;
    hN[t] = 0; hM[t] = 0;
    __syncthreads();
    const int base = blockIdx.x * 4096;
    for (int i = t; i < 4096; i += 256) {
        int e = base + i;
        if (e < E) {
            atomicAdd(&hN[nd[e] >> SH_N], 1);
            atomicAdd(&hM[he[e] >> SH_M], 1);
        }
    }
    __syncthreads();
    int cN = hN[t], cM = hM[t];
    __syncthreads();
    if (cN) hN[t] = coffN[t] + atomicAdd(&gcurN[t], cN);   // absolute staging cursor
    if (cM) hM[t] = coffM[t] + atomicAdd(&gcurM[t], cM);
    __syncthreads();
    for (int i = t; i < 4096; i += 256) {
        int e = base + i;
        if (e < E) {
            int d = nd[e], h = he[e];
            int pN = atomicAdd(&hN[d >> SH_N], 1);
            stN[pN] = ((unsigned int)(d & 511) << 14) | (unsigned int)h;   // h < 16384
            int pM = atomicAdd(&hM[h >> SH_M], 1);
            stM[pM] = ((unsigned int)(h & 63) << 17) | (unsigned int)d;    // d < 131072
        }
    }
}

// pass2: per bucket -> fine CSR offsets (LDS hist + scan) + block-local scatter.
__launch_bounds__(256)
__global__ void bucket_build(const unsigned int* __restrict__ stN,
                             const unsigned int* __restrict__ stM,
                             const int* __restrict__ coffN, const int* __restrict__ coffM,
                             int* __restrict__ nd_off, int* __restrict__ he_off,
                             int* __restrict__ nd_adj, int* __restrict__ he_adj) {
    __shared__ int cnt[512];
    __shared__ int cur[512];
    __shared__ int ps[256];
    int b = blockIdx.x;
    const int t = threadIdx.x;
    const unsigned int* st; const int* coff; int* offout; int* adj;
    int dmin, dcnt, sshift; unsigned int smask; int ntot;
    if (b < NB_N) {
        st = stN; coff = coffN; offout = nd_off; adj = nd_adj;
        dmin = b << SH_N; dcnt = min(512, HY_N - dmin);
        sshift = 14; smask = 0x3FFFu; ntot = HY_N;
    } else {
        b -= NB_N;
        st = stM; coff = coffM; offout = he_off; adj = he_adj;
        dmin = b << SH_M; dcnt = min(64, HY_M - dmin);
        sshift = 17; smask = 0x1FFFFu; ntot = HY_M;
    }
    const int cbase = coff[b], cend = coff[b + 1];
    cnt[t] = 0; cnt[t + 256] = 0;
    __syncthreads();
    for (int k = cbase + t; k < cend; k += 256)
        atomicAdd(&cnt[st[k] >> sshift], 1);
    __syncthreads();
    // exclusive scan of cnt[0..512) -> absolute cursors
    int a0 = cnt[2 * t], a1 = cnt[2 * t + 1];
    int pair = a0 + a1;
    ps[t] = pair;
    __syncthreads();
    for (int off = 1; off < 256; off <<= 1) {
        int x = (t >= off) ? ps[t - off] : 0;
        __syncthreads(); ps[t] += x; __syncthreads();
    }
    int excl = ps[t] - pair;
    cur[2 * t]     = cbase + excl;
    cur[2 * t + 1] = cbase + excl + a0;
    __syncthreads();
    for (int i = t; i < dcnt; i += 256) offout[dmin + i] = cur[i];
    if (t == 0 && dmin + dcnt == ntot) offout[ntot] = cend;
    __syncthreads();   // offsets written before cursors mutate
    for (int k = cbase + t; k < cend; k += 256) {
        unsigned int w = st[k];
        int pos = atomicAdd(&cur[w >> sshift], 1);
        adj[pos] = (int)(w & smask);
    }
}

// ---------------- dense f32 GEMM core: K=N=128, 64-row tiles, W-only LDS -----
__device__ __forceinline__ void gemm_accum(const float* __restrict__ A,
        const float* __restrict__ W, int nrows, float* wlds,
        float (&acc)[4][4], int row0) {
    const int tid = threadIdx.x;
    const int cg = tid & 31;
    for (int i = tid; i < 4096; i += 512)
        ((float4*)wlds)[i] = ((const float4*)W)[i];
    __syncthreads();
    const float4* A0 = (const float4*)(A + (size_t)min(row0 + 0, nrows - 1) * 128);
    const float4* A1 = (const float4*)(A + (size_t)min(row0 + 1, nrows - 1) * 128);
    const float4* A2 = (const float4*)(A + (size_t)min(row0 + 2, nrows - 1) * 128);
    const float4* A3 = (const float4*)(A + (size_t)min(row0 + 3, nrows - 1) * 128);
    #pragma unroll 2
    for (int kq = 0; kq < 32; ++kq) {
        float4 ar[4] = {A0[kq], A1[kq], A2[kq], A3[kq]};    // wave-broadcast loads
        const float4* wk = (const float4*)(wlds + kq * 512);
        float4 wr[4] = {wk[cg], wk[32 + cg], wk[64 + cg], wk[96 + cg]};
        #pragma unroll
        for (int r = 0; r < 4; ++r) {
            float av[4] = {ar[r].x, ar[r].y, ar[r].z, ar[r].w};
            #pragma unroll
            for (int j = 0; j < 4; ++j) {
                float wv[4] = {wr[j].x, wr[j].y, wr[j].z, wr[j].w};
                #pragma unroll
                for (int c = 0; c < 4; ++c)
                    acc[r][c] = fmaf(av[j], wv[c], acc[r][c]);
            }
        }
    }
}

__device__ __forceinline__ void gemm_epilogue(const float* __restrict__ b,
        float* __restrict__ Cf, unsigned short* __restrict__ Cb, int ldb, int coloff,
        int nrows, float (&acc)[4][4], int row0) {
    const int cg = threadIdx.x & 31;
    const float4 bv = ((const float4*)b)[cg];
    #pragma unroll
    for (int r = 0; r < 4; ++r) {
        int gr = row0 + r;
        if (gr < nrows) {
            float o0 = acc[r][0] + bv.x, o1 = acc[r][1] + bv.y;
            float o2 = acc[r][2] + bv.z, o3 = acc[r][3] + bv.w;
            if (Cf) {
                float4 o = {o0, o1, o2, o3};
                ((float4*)(Cf + (size_t)gr * 128))[cg] = o;
            }
            if (Cb) {
                uint2 pk;
                pk.x = f2bf(o0) | (f2bf(o1) << 16);
                pk.y = f2bf(o2) | (f2bf(o3) << 16);
                *(uint2*)(Cb + (size_t)gr * ldb + coloff + cg * 4) = pk;
            }
        }
    }
}

__launch_bounds__(512)
__global__ void gemm_uni(const float* __restrict__ A, const float* __restrict__ W,
                         const float* __restrict__ b, float* __restrict__ Cf,
                         unsigned short* __restrict__ Cb, int ldb, int coloff, int nrows) {
    __shared__ __align__(16) float wlds[16384];
    const int rs = threadIdx.x >> 5;
    const int row0 = blockIdx.x * 64 + rs * 4;
    float acc[4][4] = {};
    gemm_accum(A, W, nrows, wlds, acc, row0);
    gemm_epilogue(b, Cf, Cb, ldb, coloff, nrows, acc, row0);
}

// batched: y=0 -> kv k-half (bf16), y=1 -> kv v-half (bf16), y=2 -> qt_e f32
__launch_bounds__(512)
__global__ void gemm_x3(const float* __restrict__ A,
        const float* __restrict__ W5, const float* __restrict__ b5,
        const float* __restrict__ W6, const float* __restrict__ b6,
        const float* __restrict__ W12, const float* __restrict__ b12,
        unsigned short* __restrict__ kv, float* __restrict__ qt, int nrows) {
    __shared__ __align__(16) float wlds[16384];
    const int rs = threadIdx.x >> 5;
    const int row0 = blockIdx.x * 64 + rs * 4;
    const int y = blockIdx.y;
    const float* W = y == 0 ? W5 : (y == 1 ? W6 : W12);
    const float* b = y == 0 ? b5 : (y == 1 ? b6 : b12);
    float acc[4][4] = {};
    gemm_accum(A, W, nrows, wlds, acc, row0);
    if (y == 2) gemm_epilogue(b, qt, nullptr, 0, 0, nrows, acc, row0);
    else        gemm_epilogue(b, nullptr, kv, 256, y == 0 ? 0 : 128, nrows, acc, row0);
}

// ---------------- tiny precompute kernels ----------------
__global__ void transpose128(const float* __restrict__ W, float* __restrict__ WT) {
    int i = blockIdx.x * 256 + threadIdx.x;   // 64 blocks
    if (i < 128 * 128) WT[(i & 127) * 128 + (i >> 7)] = W[i];
}

__global__ void prep_vecs(const float* __restrict__ W1, const float* __restrict__ W2,
                          const float* __restrict__ b1, const float* __restrict__ b2,
                          float* __restrict__ b12, float* __restrict__ w1b2,
                          float* __restrict__ s12) {
    int t = threadIdx.x;  // 256
    if (t < 128) {
        float acc = 0.f;
        for (int j = 0; j < 128; ++j) acc += W2[t * 128 + j] * b1[j];
        b12[t] = acc;
    } else {
        int k = t - 128;
        float acc = 0.f;
        for (int j = 0; j < 128; ++j) acc += W1[k * 128 + j] * b2[j];
        w1b2[k] = acc;
    }
    if (t == 0) {
        float acc = 0.f;
        for (int j = 0; j < 128; ++j) acc += b1[j] * b2[j];
        *s12 = acc;
    }
}

__global__ void prep_w3c(const float* __restrict__ W3, const float* __restrict__ Wc,
                         const float* __restrict__ b3, float* __restrict__ W3c,
                         float* __restrict__ b3c) {
    int i = blockIdx.x * 256 + threadIdx.x;
    if (i < 1280) {
        int k = i / 10, c = i % 10;
        float acc = 0.f;
        for (int j = 0; j < 128; ++j) acc += W3[k * 128 + j] * Wc[j * 10 + c];
        W3c[i] = acc;
    } else if (i < 1290) {
        int c = i - 1280;
        float acc = 0.f;
        for (int j = 0; j < 128; ++j) acc += b3[j] * Wc[j * 10 + c];
        b3c[c] = acc;
    }
}

// c_e[m] = feat_e[m].w1b2 + s12   (one wave per row)
__launch_bounds__(256)
__global__ void dotc(const float* __restrict__ X, const float* __restrict__ w1b2,
                     const float* __restrict__ s12, float* __restrict__ c_e, int M) {
    int w = (blockIdx.x * blockDim.x + threadIdx.x) >> 6;
    int lane = threadIdx.x & 63;
    if (w >= M) return;
    float2 r = ((const float2*)(X + (size_t)w * 128))[lane];
    float2 u = ((const float2*)w1b2)[lane];
    float d = r.x * u.x + r.y * u.y;
    #pragma unroll
    for (int o = 32; o; o >>= 1) d += __shfl_xor(d, o, 64);
    if (lane == 0) c_e[w] = d + *s12;
}

// ---------------- stage 1: hyperedge -> node --------------------------------
// 16-lane group per segment (4 segments/wave). lane j owns dims 8j..8j+7.
__launch_bounds__(256)
__global__ void attn_s1(const unsigned int* __restrict__ qv,   // N x 64 words
                        const unsigned int* __restrict__ kv,   // M x 128 words (k|v)
                        const int* __restrict__ off, const int* __restrict__ adj,
                        unsigned int* __restrict__ fv,         // N x 64 words
                        int nseg, float scale) {
    int seg = (blockIdx.x * blockDim.x + threadIdx.x) >> 4;
    int j = threadIdx.x & 15;
    if (seg >= nseg) return;
    int beg = off[seg], end = off[seg + 1];
    uint4 qw = ((const uint4*)(qv + (size_t)seg * 64))[j];
    float2 q0 = bf2x2(qw.x), q1 = bf2x2(qw.y), q2 = bf2x2(qw.z), q3 = bf2x2(qw.w);
    float m = -INFINITY, l = 0.f;
    float a[8] = {};
    if (beg < end) {
        int s = adj[beg];
        uint4 kw = ((const uint4*)(kv + (size_t)s * 128))[j];
        uint4 vw = ((const uint4*)(kv + (size_t)s * 128 + 64))[j];
        for (int i = beg; i < end; ++i) {
            uint4 kc = kw, vc = vw;
            if (i + 1 < end) {                     // group-uniform prefetch
                int s2 = adj[i + 1];
                kw = ((const uint4*)(kv + (size_t)s2 * 128))[j];
                vw = ((const uint4*)(kv + (size_t)s2 * 128 + 64))[j];
            }
            float2 k0 = bf2x2(kc.x), k1 = bf2x2(kc.y), k2 = bf2x2(kc.z), k3 = bf2x2(kc.w);
            float d = k0.x * q0.x + k0.y * q0.y + k1.x * q1.x + k1.y * q1.y
                    + k2.x * q2.x + k2.y * q2.y + k3.x * q3.x + k3.y * q3.y;
            d += __shfl_xor(d, 8); d += __shfl_xor(d, 4);
            d += __shfl_xor(d, 2); d += __shfl_xor(d, 1);
            d = (d >= 0.f ? d : 0.01f * d) * scale;
            float2 v0 = bf2x2(vc.x), v1 = bf2x2(vc.y), v2 = bf2x2(vc.z), v3 = bf2x2(vc.w);
            float vf[8] = {v0.x, v0.y, v1.x, v1.y, v2.x, v2.y, v3.x, v3.y};
            float mn = fmaxf(m, d);
            float r = __expf(m - mn);              // first iter: exp(-inf)=0
            float p = __expf(d - mn);
            l = l * r + p;
            #pragma unroll
            for (int t = 0; t < 8; ++t) a[t] = a[t] * r + p * vf[t];
            m = mn;
        }
    }
    float inv = (l > 0.f) ? 1.f / l : 0.f;
    uint4 o;
    o.x = f2bf(a[0] * inv) | (f2bf(a[1] * inv) << 16);
    o.y = f2bf(a[2] * inv) | (f2bf(a[3] * inv) << 16);
    o.z = f2bf(a[4] * inv) | (f2bf(a[5] * inv) << 16);
    o.w = f2bf(a[6] * inv) | (f2bf(a[7] * inv) << 16);
    ((uint4*)(fv + (size_t)seg * 64))[j] = o;
}

// ---------------- stage 2: node -> hyperedge --------------------------------
// one 256-thread block per segment = 16 groups strided over the edge list.
__launch_bounds__(256)
__global__ void attn_s2(const float* __restrict__ QT, const float* __restrict__ cvec,
                        const unsigned int* __restrict__ fv,   // N x 64 words
                        const int* __restrict__ off, const int* __restrict__ adj,
                        float* __restrict__ agg, float* __restrict__ flag, float scale) {
    __shared__ float sm[16], sl[16];
    __shared__ float sacc[16][16][9];              // pad 9: conflict-free scalar access
    const int seg = blockIdx.x;
    const int g = threadIdx.x >> 4;                // group 0..15
    const int j = threadIdx.x & 15;                // dims 8j..8j+7
    const int beg = off[seg], end = off[seg + 1];
    const float4 qa = ((const float4*)(QT + (size_t)seg * 128 + 8 * j))[0];
    const float4 qb = ((const float4*)(QT + (size_t)seg * 128 + 8 * j))[1];
    const float cadd = cvec[seg];
    float m = -INFINITY, l = 0.f;
    float a[8] = {};
    int i = beg + g;
    if (i < end) {
        int s = adj[i];
        uint4 rw = ((const uint4*)(fv + (size_t)s * 64))[j];
        for (; i < end; i += 16) {
            uint4 rc = rw;
            if (i + 16 < end) {                    // group-uniform prefetch
                int s2 = adj[i + 16];
                rw = ((const uint4*)(fv + (size_t)s2 * 64))[j];
            }
            float2 r0 = bf2x2(rc.x), r1 = bf2x2(rc.y), r2 = bf2x2(rc.z), r3 = bf2x2(rc.w);
            float rf[8] = {r0.x, r0.y, r1.x, r1.y, r2.x, r2.y, r3.x, r3.y};
            float d = rf[0] * qa.x + rf[1] * qa.y + rf[2] * qa.z + rf[3] * qa.w
                    + rf[4] * qb.x + rf[5] * qb.y + rf[6] * qb.z + rf[7] * qb.w;
            d += __shfl_xor(d, 8); d += __shfl_xor(d, 4);
            d += __shfl_xor(d, 2); d += __shfl_xor(d, 1);
            d += cadd;
            d = (d >= 0.f ? d : 0.01f * d) * scale;
            float mn = fmaxf(m, d);
            float r = __expf(m - mn);
            float p = __expf(d - mn);
            l = l * r + p;
            #pragma unroll
            for (int t = 0; t < 8; ++t) a[t] = a[t] * r + p * rf[t];
            m = mn;
        }
    }
    if (j == 0) { sm[g] = m; sl[g] = l; }          // m,l group-uniform
    #pragma unroll
    for (int t = 0; t < 8; ++t) sacc[g][j][t] = a[t];
    __syncthreads();
    if (threadIdx.x < 16) {                        // lane = j, merge 16 states
        float M2 = -INFINITY;
        #pragma unroll 4
        for (int gg = 0; gg < 16; ++gg) if (sl[gg] > 0.f) M2 = fmaxf(M2, sm[gg]);
        float L = 0.f;
        float acc[8] = {};
        #pragma unroll 4
        for (int gg = 0; gg < 16; ++gg) {
            float f = (sl[gg] > 0.f) ? __expf(sm[gg] - M2) : 0.f;
            L += f * sl[gg];
            #pragma unroll
            for (int t = 0; t < 8; ++t) acc[t] += f * sacc[gg][threadIdx.x][t];
        }
        float inv = (L > 0.f) ? 1.f / L : 0.f;
        float4 o1 = {acc[0] * inv, acc[1] * inv, acc[2] * inv, acc[3] * inv};
        float4 o2 = {acc[4] * inv, acc[5] * inv, acc[6] * inv, acc[7] * inv};
        ((float4*)(agg + (size_t)seg * 128 + 8 * threadIdx.x))[0] = o1;
        ((float4*)(agg + (size_t)seg * 128 + 8 * threadIdx.x))[1] = o2;
        if (threadIdx.x == 0) flag[seg] = (L > 0.f) ? 1.f : 0.f;
    }
}

// pred[m,c] = agg[m].W3c[:,c] + flag[m]*b3c[c] + bc[c]
__global__ void head2(const float* __restrict__ agg, const float* __restrict__ flag,
                      const float* __restrict__ W3c, const float* __restrict__ b3c,
                      const float* __restrict__ bc, float* __restrict__ out, int M) {
    int t = blockIdx.x * blockDim.x + threadIdx.x;
    if (t >= M * 10) return;
    int row = t / 10, c = t % 10;
    float acc = bc[c] + flag[row] * b3c[c];
    #pragma unroll 8
    for (int k = 0; k < 128; ++k)
        acc = fmaf(agg[(size_t)row * 128 + k], W3c[k * 10 + c], acc);
    out[t] = acc;
}

extern "C" void kernel_launch(void* const* d_in, const int* in_sizes, int n_in,
                              void* d_out, int out_size, void* d_ws, size_t ws_size,
                              hipStream_t stream) {
    const float* vfeat = (const float*)d_in[0];
    const float* efeat = (const float*)d_in[1];
    const int*   he    = (const int*)d_in[2];
    const int*   nd    = (const int*)d_in[3];
    const float* Wfl = (const float*)d_in[6],  *bfl = (const float*)d_in[7];
    const float* W1  = (const float*)d_in[8],  *b1  = (const float*)d_in[9];
    const float* W2  = (const float*)d_in[10], *b2  = (const float*)d_in[11];
    const float* W3  = (const float*)d_in[12], *b3  = (const float*)d_in[13];
    const float* W4  = (const float*)d_in[14], *b4  = (const float*)d_in[15];
    const float* W5  = (const float*)d_in[16], *b5  = (const float*)d_in[17];
    const float* W6  = (const float*)d_in[18], *b6  = (const float*)d_in[19];
    const float* Wc  = (const float*)d_in[20], *bc  = (const float*)d_in[21];
    float* out = (float*)d_out;
    float* ws  = (float*)d_ws;

    const int M = HY_M, N = HY_N, E = HY_E;

    // -------- workspace layout (float units) --------
    float* feat_e = ws + 0;          // 1.28M
    float* qt_e   = ws + 1280000;    // 1.28M
    float* agg    = ws + 2560000;    // 1.28M
    float* c_e    = ws + 3840000;    // 10K
    float* flag   = ws + 3850000;    // 10K
    float* W2T    = ws + 3860000;    // 16384
    float* W12    = ws + 3876384;    // 16384
    float* W3c    = ws + 3892768;    // 1280
    float* b3c    = ws + 3894048;    // 16
    float* b12    = ws + 3894064;    // 128
    float* w1b2   = ws + 3894192;    // 128
    float* s12    = ws + 3894320;    // 4
    float* zeros  = ws + 3894324;    // 128 (+pad)
    unsigned int* qv_bf = (unsigned int*)(ws + 3894512);   // N*64 words = 6.4M
    unsigned int* kv_bf = qv_bf + (size_t)N * 64;          // M*128 words = 1.28M
    unsigned int* fv_bf = kv_bf + (size_t)M * 128;         // N*64 words = 6.4M
    int* nd_off = (int*)(fv_bf + (size_t)N * 64);          // 100001
    int* he_off = nd_off + 100001;                          // 10001
    int* nd_adj = he_off + 10001;                           // 640000 (stores he[e])
    int* he_adj = nd_adj + 640000;                          // 640000 (stores nd[e])
    unsigned int* stN = (unsigned int*)(he_adj + 640000);   // 640000 staging
    unsigned int* stM = stN + 640000;                       // 640000 staging
    int* gcntN = (int*)(stM + 640000);                      // 256
    int* gcntM = gcntN + 256;                               // 256
    int* gcurN = gcntM + 256;                               // 256
    int* gcurM = gcurN + 256;                               // 256
    int* coffN = gcurM + 256;                               // 256 (197 used)
    int* coffM = coffN + 256;                               // 256 (158 used)

    const float scale = 0.08838834764831843f;  // 1/sqrt(128)
    const int nchunk = (E + 4095) / 4096;      // 157

    // -------- CSR build: bucketed counting sort (both orientations) --------
    zero_ints<<<4, 256, 0, stream>>>(gcntN, 1024);          // gcntN/M + gcurN/M
    coarse_hist<<<nchunk, 256, 0, stream>>>(nd, he, gcntN, gcntM, E);
    coarse_scan<<<2, 256, 0, stream>>>(gcntN, gcntM, coffN, coffM, E);
    part_scatter<<<nchunk, 256, 0, stream>>>(nd, he, coffN, coffM,
                                             gcurN, gcurM, stN, stM, E);
    bucket_build<<<NB_N + NB_M, 256, 0, stream>>>(stN, stM, coffN, coffM,
                                                  nd_off, he_off, nd_adj, he_adj);

    // -------- weight precomputes --------
    transpose128<<<64, 256, 0, stream>>>(W2, W2T);
    fillk<<<1, 128, 0, stream>>>(zeros, 0.f, 128);
    prep_vecs<<<1, 256, 0, stream>>>(W1, W2, b1, b2, b12, w1b2, s12);
    gemm_uni<<<2, 512, 0, stream>>>(W1, W2T, zeros, W12, nullptr, 0, 0, 128);
    prep_w3c<<<6, 256, 0, stream>>>(W3, Wc, b3, W3c, b3c);

    // -------- dense layers --------
    gemm_uni<<<(M + 63) / 64, 512, 0, stream>>>(efeat, Wfl, bfl, feat_e,
                                                nullptr, 0, 0, M);
    gemm_x3<<<dim3((M + 63) / 64, 3), 512, 0, stream>>>(
        feat_e, W5, b5, W6, b6, W12, b12, (unsigned short*)kv_bf, qt_e, M);
    dotc<<<(M * 64 + 255) / 256, 256, 0, stream>>>(feat_e, w1b2, s12, c_e, M);
    gemm_uni<<<(N + 63) / 64, 512, 0, stream>>>(vfeat, W4, b4, nullptr,
                                                (unsigned short*)qv_bf, 128, 0, N);

    // -------- stage 1: hyperedge -> node (16-lane groups, 4 seg/wave) --------
    attn_s1<<<(N * 16 + 255) / 256, 256, 0, stream>>>(
        qv_bf, kv_bf, nd_off, nd_adj, fv_bf, N, scale);

    // -------- stage 2: node -> hyperedge (16 groups per block) --------
    attn_s2<<<M, 256, 0, stream>>>(qt_e, c_e, fv_bf, he_off, he_adj, agg, flag, scale);

    // -------- head --------
    head2<<<(M * 10 + 255) / 256, 256, 0, stream>>>(agg, flag, W3c, b3c, bc, out, M);
}

// Round 8
// 220.329 us; speedup vs baseline: 5.6064x; 1.2417x over previous
//
#include <hip/hip_runtime.h>
#include <hip/hip_bf16.h>
#include <math.h>

// ---------------------------------------------------------------------------
// Seq_HyGAN round 8: eliminate the N-row GEMM entirely.
//  stage1 logit: dot(k_e[he], q_v[nd]) = vfeat[nd]·kt_e[he] + ck[he]
//    kt_e = feat_e@(W5@W4^T) + W4@b5   (M-row, folded into gemm_x3 k-half)
//    ck   = feat_e·(W5@b4) + b5·b4     (fused dotc2)
//  attn_s1 streams raw vfeat f32 as query; q_v never materialized.
//  CSR counting-sort build + 16-lane-group attention from rounds 6/7 kept.
// ---------------------------------------------------------------------------

#define HY_M 10000
#define HY_N 100000
#define HY_E 640000

#define SH_N 9              // node bucket width 512
#define NB_N 196            // ceil(100000/512)
#define SH_M 6              // hedge bucket width 64
#define NB_M 157            // ceil(10000/64)

// ---- bf16 helpers (manual, RN) ----
__device__ __forceinline__ unsigned int f2bf(float x) {
    unsigned int u = __float_as_uint(x);
    return (u + 0x7fffu + ((u >> 16) & 1u)) >> 16;
}
__device__ __forceinline__ float2 bf2x2(unsigned int w) {   // elems (2l, 2l+1)
    float lo = __uint_as_float(w << 16);
    float hi = __uint_as_float(w & 0xffff0000u);
    return make_float2(lo, hi);
}

// ---------------- small utility kernels ----------------
__global__ void zero_ints(int* __restrict__ p, int n) {
    int i = blockIdx.x * blockDim.x + threadIdx.x;
    if (i < n) p[i] = 0;
}

__global__ void fillk(float* __restrict__ p, float v, int n) {
    int stride = gridDim.x * blockDim.x;
    for (int i = blockIdx.x * blockDim.x + threadIdx.x; i < n; i += stride) p[i] = v;
}

// ---------------- CSR build: bucketed counting sort ----------------
__launch_bounds__(256)
__global__ void coarse_hist(const int* __restrict__ nd, const int* __restrict__ he,
                            int* __restrict__ gcntN, int* __restrict__ gcntM, int E) {
    __shared__ int hN[256], hM[256];
    const int t = threadIdx.x;
    hN[t] = 0; hM[t] = 0;
    __syncthreads();
    const int base = blockIdx.x * 4096;
    for (int i = t; i < 4096; i += 256) {
        int e = base + i;
        if (e < E) {
            atomicAdd(&hN[nd[e] >> SH_N], 1);
            atomicAdd(&hM[he[e] >> SH_M], 1);
        }
    }
    __syncthreads();
    if (hN[t]) atomicAdd(&gcntN[t], hN[t]);
    if (hM[t]) atomicAdd(&gcntM[t], hM[t]);
}

__global__ void coarse_scan(const int* __restrict__ gcntN, const int* __restrict__ gcntM,
                            int* __restrict__ coffN, int* __restrict__ coffM, int E) {
    __shared__ int s[256];
    const int* g = blockIdx.x ? gcntM : gcntN;
    int* o = blockIdx.x ? coffM : coffN;
    const int nb = blockIdx.x ? NB_M : NB_N;
    const int t = threadIdx.x;
    int v = (t < nb) ? g[t] : 0;
    int orig = v;
    s[t] = v; __syncthreads();
    for (int off = 1; off < 256; off <<= 1) {
        int x = (t >= off) ? s[t - off] : 0;
        __syncthreads(); s[t] += x; __syncthreads();
    }
    if (t < nb) o[t] = s[t] - orig;
    if (t == 0) o[nb] = E;
}

__launch_bounds__(256)
__global__ void part_scatter(const int* __restrict__ nd, const int* __restrict__ he,
                             const int* __restrict__ coffN, const int* __restrict__ coffM,
                             int* __restrict__ gcurN, int* __restrict__ gcurM,
                             unsigned int* __restrict__ stN, unsigned int* __restrict__ stM,
                             int E) {
    __shared__ int hN[256], hM[256];
    const int t = threadIdx.x;
    hN[t] = 0; hM[t] = 0;
    __syncthreads();
    const int base = blockIdx.x * 4096;
    for (int i = t; i < 4096; i += 256) {
        int e = base + i;
        if (e < E) {
            atomicAdd(&hN[nd[e] >> SH_N], 1);
            atomicAdd(&hM[he[e] >> SH_M], 1);
        }
    }
    __syncthreads();
    int cN = hN[t], cM = hM[t];
    __syncthreads();
    if (cN) hN[t] = coffN[t] + atomicAdd(&gcurN[t], cN);
    if (cM) hM[t] = coffM[t] + atomicAdd(&gcurM[t], cM);
    __syncthreads();
    for (int i = t; i < 4096; i += 256) {
        int e = base + i;
        if (e < E) {
            int d = nd[e], h = he[e];
            int pN = atomicAdd(&hN[d >> SH_N], 1);
            stN[pN] = ((unsigned int)(d & 511) << 14) | (unsigned int)h;
            int pM = atomicAdd(&hM[h >> SH_M], 1);
            stM[pM] = ((unsigned int)(h & 63) << 17) | (unsigned int)d;
        }
    }
}

__launch_bounds__(256)
__global__ void bucket_build(const unsigned int* __restrict__ stN,
                             const unsigned int* __restrict__ stM,
                             const int* __restrict__ coffN, const int* __restrict__ coffM,
                             int* __restrict__ nd_off, int* __restrict__ he_off,
                             int* __restrict__ nd_adj, int* __restrict__ he_adj) {
    __shared__ int cnt[512];
    __shared__ int cur[512];
    __shared__ int ps[256];
    int b = blockIdx.x;
    const int t = threadIdx.x;
    const unsigned int* st; const int* coff; int* offout; int* adj;
    int dmin, dcnt, sshift; unsigned int smask; int ntot;
    if (b < NB_N) {
        st = stN; coff = coffN; offout = nd_off; adj = nd_adj;
        dmin = b << SH_N; dcnt = min(512, HY_N - dmin);
        sshift = 14; smask = 0x3FFFu; ntot = HY_N;
    } else {
        b -= NB_N;
        st = stM; coff = coffM; offout = he_off; adj = he_adj;
        dmin = b << SH_M; dcnt = min(64, HY_M - dmin);
        sshift = 17; smask = 0x1FFFFu; ntot = HY_M;
    }
    const int cbase = coff[b], cend = coff[b + 1];
    cnt[t] = 0; cnt[t + 256] = 0;
    __syncthreads();
    for (int k = cbase + t; k < cend; k += 256)
        atomicAdd(&cnt[st[k] >> sshift], 1);
    __syncthreads();
    int a0 = cnt[2 * t], a1 = cnt[2 * t + 1];
    int pair = a0 + a1;
    ps[t] = pair;
    __syncthreads();
    for (int off = 1; off < 256; off <<= 1) {
        int x = (t >= off) ? ps[t - off] : 0;
        __syncthreads(); ps[t] += x; __syncthreads();
    }
    int excl = ps[t] - pair;
    cur[2 * t]     = cbase + excl;
    cur[2 * t + 1] = cbase + excl + a0;
    __syncthreads();
    for (int i = t; i < dcnt; i += 256) offout[dmin + i] = cur[i];
    if (t == 0 && dmin + dcnt == ntot) offout[ntot] = cend;
    __syncthreads();
    for (int k = cbase + t; k < cend; k += 256) {
        unsigned int w = st[k];
        int pos = atomicAdd(&cur[w >> sshift], 1);
        adj[pos] = (int)(w & smask);
    }
}

// ---------------- dense f32 GEMM core: K=N=128, 64-row tiles, W-only LDS -----
__device__ __forceinline__ void gemm_accum(const float* __restrict__ A,
        const float* __restrict__ W, int nrows, float* wlds,
        float (&acc)[4][4], int row0) {
    const int tid = threadIdx.x;
    const int cg = tid & 31;
    for (int i = tid; i < 4096; i += 512)
        ((float4*)wlds)[i] = ((const float4*)W)[i];
    __syncthreads();
    const float4* A0 = (const float4*)(A + (size_t)min(row0 + 0, nrows - 1) * 128);
    const float4* A1 = (const float4*)(A + (size_t)min(row0 + 1, nrows - 1) * 128);
    const float4* A2 = (const float4*)(A + (size_t)min(row0 + 2, nrows - 1) * 128);
    const float4* A3 = (const float4*)(A + (size_t)min(row0 + 3, nrows - 1) * 128);
    #pragma unroll 2
    for (int kq = 0; kq < 32; ++kq) {
        float4 ar[4] = {A0[kq], A1[kq], A2[kq], A3[kq]};    // wave-broadcast loads
        const float4* wk = (const float4*)(wlds + kq * 512);
        float4 wr[4] = {wk[cg], wk[32 + cg], wk[64 + cg], wk[96 + cg]};
        #pragma unroll
        for (int r = 0; r < 4; ++r) {
            float av[4] = {ar[r].x, ar[r].y, ar[r].z, ar[r].w};
            #pragma unroll
            for (int j = 0; j < 4; ++j) {
                float wv[4] = {wr[j].x, wr[j].y, wr[j].z, wr[j].w};
                #pragma unroll
                for (int c = 0; c < 4; ++c)
                    acc[r][c] = fmaf(av[j], wv[c], acc[r][c]);
            }
        }
    }
}

__device__ __forceinline__ void gemm_epilogue(const float* __restrict__ b,
        float* __restrict__ Cf, unsigned short* __restrict__ Cb, int ldb, int coloff,
        int nrows, float (&acc)[4][4], int row0) {
    const int cg = threadIdx.x & 31;
    const float4 bv = ((const float4*)b)[cg];
    #pragma unroll
    for (int r = 0; r < 4; ++r) {
        int gr = row0 + r;
        if (gr < nrows) {
            float o0 = acc[r][0] + bv.x, o1 = acc[r][1] + bv.y;
            float o2 = acc[r][2] + bv.z, o3 = acc[r][3] + bv.w;
            if (Cf) {
                float4 o = {o0, o1, o2, o3};
                ((float4*)(Cf + (size_t)gr * 128))[cg] = o;
            }
            if (Cb) {
                uint2 pk;
                pk.x = f2bf(o0) | (f2bf(o1) << 16);
                pk.y = f2bf(o2) | (f2bf(o3) << 16);
                *(uint2*)(Cb + (size_t)gr * ldb + coloff + cg * 4) = pk;
            }
        }
    }
}

__launch_bounds__(512)
__global__ void gemm_uni(const float* __restrict__ A, const float* __restrict__ W,
                         const float* __restrict__ b, float* __restrict__ Cf,
                         unsigned short* __restrict__ Cb, int ldb, int coloff, int nrows) {
    __shared__ __align__(16) float wlds[16384];
    const int rs = threadIdx.x >> 5;
    const int row0 = blockIdx.x * 64 + rs * 4;
    float acc[4][4] = {};
    gemm_accum(A, W, nrows, wlds, acc, row0);
    gemm_epilogue(b, Cf, Cb, ldb, coloff, nrows, acc, row0);
}

// two tiny 128x128 weight-product GEMMs in one launch (y=0: W12, y=1: W54)
__launch_bounds__(512)
__global__ void gemm_pair(const float* __restrict__ Aa, const float* __restrict__ Wa,
                          float* __restrict__ Ca,
                          const float* __restrict__ Ab, const float* __restrict__ Wb,
                          float* __restrict__ Cb2, const float* __restrict__ zb) {
    __shared__ __align__(16) float wlds[16384];
    const int rs = threadIdx.x >> 5;
    const int row0 = blockIdx.x * 64 + rs * 4;
    const float* A = blockIdx.y ? Ab : Aa;
    const float* W = blockIdx.y ? Wb : Wa;
    float* C = blockIdx.y ? Cb2 : Ca;
    float acc[4][4] = {};
    gemm_accum(A, W, 128, wlds, acc, row0);
    gemm_epilogue(zb, C, nullptr, 0, 0, 128, acc, row0);
}

// batched: y=0 -> kv kt-half (W54,b54 bf16), y=1 -> kv v-half (W6,b6 bf16),
//          y=2 -> qt_e f32 (W12,b12)
__launch_bounds__(512)
__global__ void gemm_x3(const float* __restrict__ A,
        const float* __restrict__ W54, const float* __restrict__ b54,
        const float* __restrict__ W6, const float* __restrict__ b6,
        const float* __restrict__ W12, const float* __restrict__ b12,
        unsigned short* __restrict__ kv, float* __restrict__ qt, int nrows) {
    __shared__ __align__(16) float wlds[16384];
    const int rs = threadIdx.x >> 5;
    const int row0 = blockIdx.x * 64 + rs * 4;
    const int y = blockIdx.y;
    const float* W = y == 0 ? W54 : (y == 1 ? W6 : W12);
    const float* b = y == 0 ? b54 : (y == 1 ? b6 : b12);
    float acc[4][4] = {};
    gemm_accum(A, W, nrows, wlds, acc, row0);
    if (y == 2) gemm_epilogue(b, qt, nullptr, 0, 0, nrows, acc, row0);
    else        gemm_epilogue(b, nullptr, kv, 256, y == 0 ? 0 : 128, nrows, acc, row0);
}

// ---------------- tiny precompute kernels ----------------
// transpose W2 and W4 in one launch
__global__ void transpose2(const float* __restrict__ W2, const float* __restrict__ W4,
                           float* __restrict__ W2T, float* __restrict__ W4T) {
    int i = blockIdx.x * 256 + threadIdx.x;   // 64 x-blocks
    const float* s = blockIdx.y ? W4 : W2;
    float* d = blockIdx.y ? W4T : W2T;
    if (i < 128 * 128) d[(i & 127) * 128 + (i >> 7)] = s[i];
}

// bXY = WY@bX ; wXbY = WX@bY ; sXY = bX.bY   (generic fold helper)
__global__ void prep_vecs(const float* __restrict__ WX, const float* __restrict__ WY,
                          const float* __restrict__ bX, const float* __restrict__ bY,
                          float* __restrict__ bXY, float* __restrict__ wXbY,
                          float* __restrict__ sXY) {
    int t = threadIdx.x;  // 256
    if (t < 128) {
        float acc = 0.f;
        for (int j = 0; j < 128; ++j) acc += WY[t * 128 + j] * bX[j];
        bXY[t] = acc;
    } else {
        int k = t - 128;
        float acc = 0.f;
        for (int j = 0; j < 128; ++j) acc += WX[k * 128 + j] * bY[j];
        wXbY[k] = acc;
    }
    if (t == 0) {
        float acc = 0.f;
        for (int j = 0; j < 128; ++j) acc += bX[j] * bY[j];
        *sXY = acc;
    }
}

__global__ void prep_w3c(const float* __restrict__ W3, const float* __restrict__ Wc,
                         const float* __restrict__ b3, float* __restrict__ W3c,
                         float* __restrict__ b3c) {
    int i = blockIdx.x * 256 + threadIdx.x;
    if (i < 1280) {
        int k = i / 10, c = i % 10;
        float acc = 0.f;
        for (int j = 0; j < 128; ++j) acc += W3[k * 128 + j] * Wc[j * 10 + c];
        W3c[i] = acc;
    } else if (i < 1290) {
        int c = i - 1280;
        float acc = 0.f;
        for (int j = 0; j < 128; ++j) acc += b3[j] * Wc[j * 10 + c];
        b3c[c] = acc;
    }
}

// two dots per feat_e row: o1 = X.u1 + s1, o2 = X.u2 + s2  (one wave per row)
__launch_bounds__(256)
__global__ void dotc2(const float* __restrict__ X,
                      const float* __restrict__ u1, const float* __restrict__ s1v,
                      const float* __restrict__ u2, const float* __restrict__ s2v,
                      float* __restrict__ o1, float* __restrict__ o2, int M) {
    int w = (blockIdx.x * blockDim.x + threadIdx.x) >> 6;
    int lane = threadIdx.x & 63;
    if (w >= M) return;
    float2 r = ((const float2*)(X + (size_t)w * 128))[lane];
    float2 a1 = ((const float2*)u1)[lane];
    float2 a2 = ((const float2*)u2)[lane];
    float d1 = r.x * a1.x + r.y * a1.y;
    float d2 = r.x * a2.x + r.y * a2.y;
    #pragma unroll
    for (int o = 32; o; o >>= 1) {
        d1 += __shfl_xor(d1, o, 64);
        d2 += __shfl_xor(d2, o, 64);
    }
    if (lane == 0) { o1[w] = d1 + *s1v; o2[w] = d2 + *s2v; }
}

// ---------------- stage 1: hyperedge -> node --------------------------------
// 16-lane group per segment; query = raw vfeat row (f32); gather kt|v + ck.
__launch_bounds__(256)
__global__ void attn_s1(const float* __restrict__ vf,          // N x 128 f32
                        const unsigned int* __restrict__ kv,   // M x 128 words (kt|v)
                        const float* __restrict__ ck,          // M
                        const int* __restrict__ off, const int* __restrict__ adj,
                        unsigned int* __restrict__ fv,         // N x 64 words
                        int nseg, float scale) {
    int seg = (blockIdx.x * blockDim.x + threadIdx.x) >> 4;
    int j = threadIdx.x & 15;
    if (seg >= nseg) return;
    int beg = off[seg], end = off[seg + 1];
    const float4 qa = ((const float4*)(vf + (size_t)seg * 128 + 8 * j))[0];
    const float4 qb = ((const float4*)(vf + (size_t)seg * 128 + 8 * j))[1];
    float m = -INFINITY, l = 0.f;
    float a[8] = {};
    if (beg < end) {
        int s = adj[beg];
        uint4 kw = ((const uint4*)(kv + (size_t)s * 128))[j];
        uint4 vw = ((const uint4*)(kv + (size_t)s * 128 + 64))[j];
        float ckn = ck[s];
        for (int i = beg; i < end; ++i) {
            uint4 kc = kw, vc = vw;
            float ckc = ckn;
            if (i + 1 < end) {                     // group-uniform prefetch
                int s2 = adj[i + 1];
                kw = ((const uint4*)(kv + (size_t)s2 * 128))[j];
                vw = ((const uint4*)(kv + (size_t)s2 * 128 + 64))[j];
                ckn = ck[s2];
            }
            float2 k0 = bf2x2(kc.x), k1 = bf2x2(kc.y), k2 = bf2x2(kc.z), k3 = bf2x2(kc.w);
            float d = k0.x * qa.x + k0.y * qa.y + k1.x * qa.z + k1.y * qa.w
                    + k2.x * qb.x + k2.y * qb.y + k3.x * qb.z + k3.y * qb.w;
            d += __shfl_xor(d, 8); d += __shfl_xor(d, 4);
            d += __shfl_xor(d, 2); d += __shfl_xor(d, 1);
            d += ckc;
            d = (d >= 0.f ? d : 0.01f * d) * scale;
            float2 v0 = bf2x2(vc.x), v1 = bf2x2(vc.y), v2 = bf2x2(vc.z), v3 = bf2x2(vc.w);
            float vfv[8] = {v0.x, v0.y, v1.x, v1.y, v2.x, v2.y, v3.x, v3.y};
            float mn = fmaxf(m, d);
            float r = __expf(m - mn);              // first iter: exp(-inf)=0
            float p = __expf(d - mn);
            l = l * r + p;
            #pragma unroll
            for (int t = 0; t < 8; ++t) a[t] = a[t] * r + p * vfv[t];
            m = mn;
        }
    }
    float inv = (l > 0.f) ? 1.f / l : 0.f;
    uint4 o;
    o.x = f2bf(a[0] * inv) | (f2bf(a[1] * inv) << 16);
    o.y = f2bf(a[2] * inv) | (f2bf(a[3] * inv) << 16);
    o.z = f2bf(a[4] * inv) | (f2bf(a[5] * inv) << 16);
    o.w = f2bf(a[6] * inv) | (f2bf(a[7] * inv) << 16);
    ((uint4*)(fv + (size_t)seg * 64))[j] = o;
}

// ---------------- stage 2: node -> hyperedge --------------------------------
__launch_bounds__(256)
__global__ void attn_s2(const float* __restrict__ QT, const float* __restrict__ cvec,
                        const unsigned int* __restrict__ fv,   // N x 64 words
                        const int* __restrict__ off, const int* __restrict__ adj,
                        float* __restrict__ agg, float* __restrict__ flag, float scale) {
    __shared__ float sm[16], sl[16];
    __shared__ float sacc[16][16][9];
    const int seg = blockIdx.x;
    const int g = threadIdx.x >> 4;
    const int j = threadIdx.x & 15;
    const int beg = off[seg], end = off[seg + 1];
    const float4 qa = ((const float4*)(QT + (size_t)seg * 128 + 8 * j))[0];
    const float4 qb = ((const float4*)(QT + (size_t)seg * 128 + 8 * j))[1];
    const float cadd = cvec[seg];
    float m = -INFINITY, l = 0.f;
    float a[8] = {};
    int i = beg + g;
    if (i < end) {
        int s = adj[i];
        uint4 rw = ((const uint4*)(fv + (size_t)s * 64))[j];
        for (; i < end; i += 16) {
            uint4 rc = rw;
            if (i + 16 < end) {
                int s2 = adj[i + 16];
                rw = ((const uint4*)(fv + (size_t)s2 * 64))[j];
            }
            float2 r0 = bf2x2(rc.x), r1 = bf2x2(rc.y), r2 = bf2x2(rc.z), r3 = bf2x2(rc.w);
            float rf[8] = {r0.x, r0.y, r1.x, r1.y, r2.x, r2.y, r3.x, r3.y};
            float d = rf[0] * qa.x + rf[1] * qa.y + rf[2] * qa.z + rf[3] * qa.w
                    + rf[4] * qb.x + rf[5] * qb.y + rf[6] * qb.z + rf[7] * qb.w;
            d += __shfl_xor(d, 8); d += __shfl_xor(d, 4);
            d += __shfl_xor(d, 2); d += __shfl_xor(d, 1);
            d += cadd;
            d = (d >= 0.f ? d : 0.01f * d) * scale;
            float mn = fmaxf(m, d);
            float r = __expf(m - mn);
            float p = __expf(d - mn);
            l = l * r + p;
            #pragma unroll
            for (int t = 0; t < 8; ++t) a[t] = a[t] * r + p * rf[t];
            m = mn;
        }
    }
    if (j == 0) { sm[g] = m; sl[g] = l; }
    #pragma unroll
    for (int t = 0; t < 8; ++t) sacc[g][j][t] = a[t];
    __syncthreads();
    if (threadIdx.x < 16) {
        float M2 = -INFINITY;
        #pragma unroll 4
        for (int gg = 0; gg < 16; ++gg) if (sl[gg] > 0.f) M2 = fmaxf(M2, sm[gg]);
        float L = 0.f;
        float acc[8] = {};
        #pragma unroll 4
        for (int gg = 0; gg < 16; ++gg) {
            float f = (sl[gg] > 0.f) ? __expf(sm[gg] - M2) : 0.f;
            L += f * sl[gg];
            #pragma unroll
            for (int t = 0; t < 8; ++t) acc[t] += f * sacc[gg][threadIdx.x][t];
        }
        float inv = (L > 0.f) ? 1.f / L : 0.f;
        float4 o1 = {acc[0] * inv, acc[1] * inv, acc[2] * inv, acc[3] * inv};
        float4 o2 = {acc[4] * inv, acc[5] * inv, acc[6] * inv, acc[7] * inv};
        ((float4*)(agg + (size_t)seg * 128 + 8 * threadIdx.x))[0] = o1;
        ((float4*)(agg + (size_t)seg * 128 + 8 * threadIdx.x))[1] = o2;
        if (threadIdx.x == 0) flag[seg] = (L > 0.f) ? 1.f : 0.f;
    }
}

// pred[m,c] = agg[m].W3c[:,c] + flag[m]*b3c[c] + bc[c]
__global__ void head2(const float* __restrict__ agg, const float* __restrict__ flag,
                      const float* __restrict__ W3c, const float* __restrict__ b3c,
                      const float* __restrict__ bc, float* __restrict__ out, int M) {
    int t = blockIdx.x * blockDim.x + threadIdx.x;
    if (t >= M * 10) return;
    int row = t / 10, c = t % 10;
    float acc = bc[c] + flag[row] * b3c[c];
    #pragma unroll 8
    for (int k = 0; k < 128; ++k)
        acc = fmaf(agg[(size_t)row * 128 + k], W3c[k * 10 + c], acc);
    out[t] = acc;
}

extern "C" void kernel_launch(void* const* d_in, const int* in_sizes, int n_in,
                              void* d_out, int out_size, void* d_ws, size_t ws_size,
                              hipStream_t stream) {
    const float* vfeat = (const float*)d_in[0];
    const float* efeat = (const float*)d_in[1];
    const int*   he    = (const int*)d_in[2];
    const int*   nd    = (const int*)d_in[3];
    const float* Wfl = (const float*)d_in[6],  *bfl = (const float*)d_in[7];
    const float* W1  = (const float*)d_in[8],  *b1  = (const float*)d_in[9];
    const float* W2  = (const float*)d_in[10], *b2  = (const float*)d_in[11];
    const float* W3  = (const float*)d_in[12], *b3  = (const float*)d_in[13];
    const float* W4  = (const float*)d_in[14], *b4  = (const float*)d_in[15];
    const float* W5  = (const float*)d_in[16], *b5  = (const float*)d_in[17];
    const float* W6  = (const float*)d_in[18], *b6  = (const float*)d_in[19];
    const float* Wc  = (const float*)d_in[20], *bc  = (const float*)d_in[21];
    float* out = (float*)d_out;
    float* ws  = (float*)d_ws;

    const int M = HY_M, N = HY_N, E = HY_E;

    // -------- workspace layout (float units) --------
    float* feat_e = ws + 0;          // 1,280,000
    float* qt_e   = ws + 1280000;    // 1,280,000
    float* agg    = ws + 2560000;    // 1,280,000
    float* c_e    = ws + 3840000;    // 10,000
    float* ck     = ws + 3850000;    // 10,000
    float* flag   = ws + 3860000;    // 10,000
    float* W2T    = ws + 3870000;    // 16384
    float* W4T    = ws + 3886384;    // 16384
    float* W12    = ws + 3902768;    // 16384
    float* W54    = ws + 3919152;    // 16384
    float* W3c    = ws + 3935536;    // 1280
    float* b3c    = ws + 3936816;    // 16
    float* b12    = ws + 3936832;    // 128
    float* w1b2   = ws + 3936960;    // 128
    float* s12    = ws + 3937088;    // 4
    float* b54    = ws + 3937092;    // 128
    float* w5b4   = ws + 3937220;    // 128
    float* s54    = ws + 3937348;    // 4
    float* zeros  = ws + 3937352;    // 128 (+pad)
    unsigned int* kv_bf = (unsigned int*)(ws + 3937480);    // M*128 = 1,280,000 words
    unsigned int* fv_bf = kv_bf + (size_t)M * 128;          // N*64 = 6,400,000 words
    int* nd_off = (int*)(fv_bf + (size_t)N * 64);           // 100,001
    int* he_off = nd_off + 100001;                           // 10,001
    int* nd_adj = he_off + 10001;                            // 640,000
    int* he_adj = nd_adj + 640000;                           // 640,000
    unsigned int* stN = (unsigned int*)(he_adj + 640000);    // 640,000 staging
    unsigned int* stM = stN + 640000;                        // 640,000 staging
    int* gcntN = (int*)(stM + 640000);                       // 256
    int* gcntM = gcntN + 256;                                // 256
    int* gcurN = gcntM + 256;                                // 256
    int* gcurM = gcurN + 256;                                // 256
    int* coffN = gcurM + 256;                                // 256 (197 used)
    int* coffM = coffN + 256;                                // 256 (158 used)

    const float scale = 0.08838834764831843f;  // 1/sqrt(128)
    const int nchunk = (E + 4095) / 4096;      // 157

    // -------- CSR build: bucketed counting sort (both orientations) --------
    zero_ints<<<4, 256, 0, stream>>>(gcntN, 1024);
    coarse_hist<<<nchunk, 256, 0, stream>>>(nd, he, gcntN, gcntM, E);
    coarse_scan<<<2, 256, 0, stream>>>(gcntN, gcntM, coffN, coffM, E);
    part_scatter<<<nchunk, 256, 0, stream>>>(nd, he, coffN, coffM,
                                             gcurN, gcurM, stN, stM, E);
    bucket_build<<<NB_N + NB_M, 256, 0, stream>>>(stN, stM, coffN, coffM,
                                                  nd_off, he_off, nd_adj, he_adj);

    // -------- weight precomputes --------
    transpose2<<<dim3(64, 2), 256, 0, stream>>>(W2, W4, W2T, W4T);
    fillk<<<1, 128, 0, stream>>>(zeros, 0.f, 128);
    prep_vecs<<<1, 256, 0, stream>>>(W1, W2, b1, b2, b12, w1b2, s12);   // stage-2 fold
    prep_vecs<<<1, 256, 0, stream>>>(W5, W4, b5, b4, b54, w5b4, s54);   // stage-1 fold
    gemm_pair<<<dim3(2, 2), 512, 0, stream>>>(W1, W2T, W12, W5, W4T, W54, zeros);
    prep_w3c<<<6, 256, 0, stream>>>(W3, Wc, b3, W3c, b3c);

    // -------- dense layers (M rows only; N-row GEMM eliminated) --------
    gemm_uni<<<(M + 63) / 64, 512, 0, stream>>>(efeat, Wfl, bfl, feat_e,
                                                nullptr, 0, 0, M);
    gemm_x3<<<dim3((M + 63) / 64, 3), 512, 0, stream>>>(
        feat_e, W54, b54, W6, b6, W12, b12, (unsigned short*)kv_bf, qt_e, M);
    dotc2<<<(M * 64 + 255) / 256, 256, 0, stream>>>(feat_e, w1b2, s12,
                                                    w5b4, s54, c_e, ck, M);

    // -------- stage 1: hyperedge -> node (streams raw vfeat) --------
    attn_s1<<<(N * 16 + 255) / 256, 256, 0, stream>>>(
        vfeat, kv_bf, ck, nd_off, nd_adj, fv_bf, N, scale);

    // -------- stage 2: node -> hyperedge --------
    attn_s2<<<M, 256, 0, stream>>>(qt_e, c_e, fv_bf, he_off, he_adj, agg, flag, scale);

    // -------- head --------
    head2<<<(M * 10 + 255) / 256, 256, 0, stream>>>(agg, flag, W3c, b3c, bc, out, M);
}